// Round 12
// baseline (1106.665 us; speedup 1.0000x reference)
//
#include <hip/hip_runtime.h>
#include <hip/hip_bf16.h>

#define L_SEQ 2048
#define BATCH 2
#define DM    1024          // d_model
#define DI    2048          // d_inner
#define DS    16            // d_state
#define DTR   64            // dt_rank
#define DBLC  96            // dt_rank + 2*d_state
#define VOCAB 32000
#define BL    (BATCH * L_SEQ)   // 4096 tokens
#define NCH   32            // scan chunks
#define CHL   (L_SEQ / NCH) // 64 steps per chunk
#define EL    8             // channels per scan block

typedef unsigned short u16;
typedef short s8v  __attribute__((ext_vector_type(8)));   // 8 bf16
typedef float f32x4 __attribute__((ext_vector_type(4)));

typedef __attribute__((address_space(1))) const void* as1cv;
typedef __attribute__((address_space(3))) void*       as3v;

// round-to-nearest-even fp32 -> bf16
static __device__ __forceinline__ u16 f2bf(float f) {
    unsigned u = __builtin_bit_cast(unsigned, f);
    u += 0x7fffu + ((u >> 16) & 1u);
    return (u16)(u >> 16);
}

// ---------------------------------------------------------------- fp32 -> bf16 converts
__global__ __launch_bounds__(256) void cvt_bf16_kernel(
    const float* __restrict__ in, u16* __restrict__ out, int n8)
{
    int i = blockIdx.x * 256 + threadIdx.x;
    if (i >= n8) return;
    const float4* p = (const float4*)in + 2 * (size_t)i;
    float4 a = p[0], b = p[1];
    s8v o;
    o[0] = (short)f2bf(a.x); o[1] = (short)f2bf(a.y);
    o[2] = (short)f2bf(a.z); o[3] = (short)f2bf(a.w);
    o[4] = (short)f2bf(b.x); o[5] = (short)f2bf(b.y);
    o[6] = (short)f2bf(b.z); o[7] = (short)f2bf(b.w);
    ((s8v*)out)[i] = o;
}

// two tensors in one dispatch (per-layer in_w + out_w)
__global__ __launch_bounds__(256) void cvt2_bf16_kernel(
    const float* __restrict__ inA, u16* __restrict__ outA, int n8A,
    const float* __restrict__ inB, u16* __restrict__ outB, int n8B)
{
    int i = blockIdx.x * 256 + threadIdx.x;
    const float* src; u16* dst; int idx;
    if (i < n8A) { src = inA; dst = outA; idx = i; }
    else if (i < n8A + n8B) { src = inB; dst = outB; idx = i - n8A; }
    else return;
    const float4* p = (const float4*)src + 2 * (size_t)idx;
    float4 a = p[0], b = p[1];
    s8v o;
    o[0] = (short)f2bf(a.x); o[1] = (short)f2bf(a.y);
    o[2] = (short)f2bf(a.z); o[3] = (short)f2bf(a.w);
    o[4] = (short)f2bf(b.x); o[5] = (short)f2bf(b.y);
    o[6] = (short)f2bf(b.z); o[7] = (short)f2bf(b.w);
    ((s8v*)dst)[idx] = o;
}

// ---------------------------------------------------------------- embedding (bf16 out)
__global__ __launch_bounds__(256) void embed_kernel(
    const int* __restrict__ tok, const float* __restrict__ emb,
    u16* __restrict__ Xb)
{
    int row = blockIdx.x;
    int t = tok[row];
    float4 v = ((const float4*)(emb + (size_t)t * DM))[threadIdx.x];
    ushort4 o;
    o.x = f2bf(v.x); o.y = f2bf(v.y); o.z = f2bf(v.z); o.w = f2bf(v.w);
    ((ushort4*)(Xb + (size_t)row * DM))[threadIdx.x] = o;
}

// ---------------------------------------------------------------- deep-pipeline GEMM
// C = A[M,K](bf16) * Bt[N,K](bf16)^T.  256x256 tile, BK=32, 512 thr = 8
// waves (2M x 4N), per-wave output 128x64 = 8x4 frags of 16x16x32.
// 4 LDS K-tile buffers (128 KB), prefetch distance 3, ONE barrier + ONE
// counted vmcnt(8) per K-step.
// HAZARD PROOF:
//  - STG at step t targets buf (t+3)%4 == (t-1)%4. All waves' ds_reads of
//    buf[(t-1)%4] happened at step t-1 BEFORE that step's end barrier
//    (own-wave lgkmcnt orders read->MFMA; barrier orders across waves).
//    Step-t STG is issued after that barrier -> safe.
//  - ds_reads at step t of buf[t%4] need tile t's stage writes complete:
//    vmcnt(8) at end of step t-1 forces tile t's 4 loads (issued t-3)
//    complete per-wave; the following barrier publishes across waves.
//  - vmcnt(8) leaves tiles t+2 (4 loads) and t+3 (4 loads) in flight
//    ACROSS the barrier (T4); tile t+1 was issued 2 full K-steps earlier
//    (~600+ cy >= HBM latency) so the wait is short.
// Proven 0-conflict XOR slot-swizzle kept (both-sides, rule #21).
// MODE 0: fp32 C0 (ldc0).  MODE 1: in_proj split u/z (C0, C1).
template<int MODE>
__global__ __launch_bounds__(512) void gemm_deep(
    const u16* __restrict__ A, int lda,
    const u16* __restrict__ Bt, int ldb,
    float* __restrict__ C0, float* __restrict__ C1,
    int ldc0, int K)
{
    __shared__ __align__(16) u16 As[4][256 * 32];   // 64 KB
    __shared__ __align__(16) u16 Bs[4][256 * 32];   // 64 KB

    const int tid  = threadIdx.x;
    const int lane = tid & 63;
    const int wv   = tid >> 6;           // 0..7
    const int bm = blockIdx.x * 256;
    const int bn = blockIdx.y * 256;

    // staging: wave wv covers rows [wv*32, wv*32+32) of A and of B (2
    // issues of 16 rows each); lane l -> row +(l>>2), LDS slot l&3 holds
    // logical k-slot (l&3)^((l>>3)&3)  (slot ^= (row>>1)&3).
    const int ks = (lane & 3) ^ ((lane >> 3) & 3);
    const int lr = lane >> 2;            // 0..15
    const u16* ag0 = A  + (size_t)(bm + wv * 32 + lr) * lda + ks * 8;
    const u16* ag1 = ag0 + 16 * (size_t)lda;
    const u16* bg0 = Bt + (size_t)(bn + wv * 32 + lr) * ldb + ks * 8;
    const u16* bg1 = bg0 + 16 * (size_t)ldb;
    const int lo0 = wv * 1024;           // 32 rows * 32 elems
    const int lo1 = wv * 1024 + 512;

    // fragment reads: row wr+m*16+li, logical slot kc stored at kc^((li>>1)&3)
    const int li = lane & 15;
    const int kc = lane >> 4;
    const int wr = (wv >> 2) * 128;      // 0,128
    const int wc = (wv & 3) * 64;        // 0,64,128,192
    const int fo = (kc ^ ((li >> 1) & 3)) * 8;

    f32x4 acc[8][4];
#pragma unroll
    for (int m = 0; m < 8; ++m)
#pragma unroll
        for (int n = 0; n < 4; ++n) acc[m][n] = (f32x4)0.f;

#define STG(buf, kk)                                                           \
    do {                                                                       \
        __builtin_amdgcn_global_load_lds((as1cv)(ag0 + (kk)),                  \
            (as3v)&As[buf][lo0], 16, 0, 0);                                    \
        __builtin_amdgcn_global_load_lds((as1cv)(ag1 + (kk)),                  \
            (as3v)&As[buf][lo1], 16, 0, 0);                                    \
        __builtin_amdgcn_global_load_lds((as1cv)(bg0 + (kk)),                  \
            (as3v)&Bs[buf][lo0], 16, 0, 0);                                    \
        __builtin_amdgcn_global_load_lds((as1cv)(bg1 + (kk)),                  \
            (as3v)&Bs[buf][lo1], 16, 0, 0);                                    \
    } while (0)

    const int nt = K >> 5;    // K/32 tiles; call sites have nt >= 32
    // prologue: stage tiles 0,1,2 (12 loads); wait tile 0 (8 in flight)
    STG(0, 0);
    STG(1, 32);
    STG(2, 64);
    asm volatile("s_waitcnt vmcnt(8)" ::: "memory");
    __builtin_amdgcn_s_barrier();
    __builtin_amdgcn_sched_barrier(0);

    for (int t = 0; t < nt; ++t) {
        if (t + 3 < nt) STG((t + 3) & 3, (t + 3) << 5);   // 3-ahead prefetch

        const u16* Ab = &As[t & 3][0];
        const u16* Bb = &Bs[t & 3][0];
        s8v af[8], bf[4];
#pragma unroll
        for (int m = 0; m < 8; ++m)
            af[m] = *(const s8v*)&Ab[(wr + m * 16 + li) * 32 + fo];
#pragma unroll
        for (int n = 0; n < 4; ++n)
            bf[n] = *(const s8v*)&Bb[(wc + n * 16 + li) * 32 + fo];

        __builtin_amdgcn_s_setprio(1);
#pragma unroll
        for (int m = 0; m < 4; ++m)
#pragma unroll
            for (int n = 0; n < 4; ++n)
                acc[m][n] = __builtin_amdgcn_mfma_f32_16x16x32_bf16(
                    af[m], bf[n], acc[m][n], 0, 0, 0);
        __builtin_amdgcn_s_setprio(0);
        __builtin_amdgcn_s_setprio(1);
#pragma unroll
        for (int m = 4; m < 8; ++m)
#pragma unroll
            for (int n = 0; n < 4; ++n)
                acc[m][n] = __builtin_amdgcn_mfma_f32_16x16x32_bf16(
                    af[m], bf[n], acc[m][n], 0, 0, 0);
        __builtin_amdgcn_s_setprio(0);

        if (t + 1 < nt) {
            if (t + 3 < nt)       // tiles t+2,t+3 stay in flight
                asm volatile("s_waitcnt vmcnt(8)" ::: "memory");
            else if (t + 2 < nt)  // only t+2 in flight
                asm volatile("s_waitcnt vmcnt(4)" ::: "memory");
            else                  // nothing beyond t+1
                asm volatile("s_waitcnt vmcnt(0)" ::: "memory");
            __builtin_amdgcn_s_barrier();
            __builtin_amdgcn_sched_barrier(0);
        }
    }
#undef STG

    // C row = bm+wr+m*16+kc*4+j, col = bn+wc+n*16+li
#pragma unroll
    for (int m = 0; m < 8; ++m) {
#pragma unroll
        for (int j = 0; j < 4; ++j) {
            int row = bm + wr + m * 16 + kc * 4 + j;
#pragma unroll
            for (int n = 0; n < 4; ++n) {
                int col = bn + wc + n * 16 + li;
                float v = acc[m][n][j];
                if (MODE == 0) {
                    C0[(size_t)row * ldc0 + col] = v;
                } else {
                    if (bn < DI) C0[(size_t)row * DI + col] = v;
                    else         C1[(size_t)row * DI + col - DI] = v;
                }
            }
        }
    }
}

// ---------------------------------------------------------------- 128^2 2-phase GEMM (out_proj)
// Round-8-proven: 2-buffer, prefetch-before-compute, vmcnt(0)+barrier/step.
// fp32 C0 + bf16 Cb outputs.
__global__ __launch_bounds__(256) void gemm_bb2(
    const u16* __restrict__ A, int lda,
    const u16* __restrict__ Bt, int ldb,
    float* __restrict__ C0, u16* __restrict__ Cb, int ldc0, int K)
{
    __shared__ __align__(16) u16 As[2][128 * 32];
    __shared__ __align__(16) u16 Bs[2][128 * 32];

    const int tid  = threadIdx.x;
    const int lane = tid & 63;
    const int wv   = tid >> 6;
    const int bm = blockIdx.x * 128;
    const int bn = blockIdx.y * 128;

    const int ks = (lane & 3) ^ ((lane >> 3) & 3);
    const int sr = wv * 32 + (lane >> 2);
    const u16* ag0 = A  + (size_t)(bm + sr) * lda + ks * 8;
    const u16* ag1 = ag0 + 16 * (size_t)lda;
    const u16* bg0 = Bt + (size_t)(bn + sr) * ldb + ks * 8;
    const u16* bg1 = bg0 + 16 * (size_t)ldb;
    const int lo0 = wv * 1024;
    const int lo1 = wv * 1024 + 512;

    const int li = lane & 15;
    const int kc = lane >> 4;
    const int wr = (wv >> 1) * 64;
    const int wc = (wv & 1) * 64;
    const int fo = (kc ^ ((li >> 1) & 3)) * 8;

    f32x4 acc[4][4];
#pragma unroll
    for (int m = 0; m < 4; ++m)
#pragma unroll
        for (int n = 0; n < 4; ++n) acc[m][n] = (f32x4)0.f;

#define STAGE(buf, kk)                                                         \
    do {                                                                       \
        __builtin_amdgcn_global_load_lds((as1cv)(ag0 + (kk)),                  \
            (as3v)&As[buf][lo0], 16, 0, 0);                                    \
        __builtin_amdgcn_global_load_lds((as1cv)(ag1 + (kk)),                  \
            (as3v)&As[buf][lo1], 16, 0, 0);                                    \
        __builtin_amdgcn_global_load_lds((as1cv)(bg0 + (kk)),                  \
            (as3v)&Bs[buf][lo0], 16, 0, 0);                                    \
        __builtin_amdgcn_global_load_lds((as1cv)(bg1 + (kk)),                  \
            (as3v)&Bs[buf][lo1], 16, 0, 0);                                    \
    } while (0)

    const int nt = K >> 5;
    STAGE(0, 0);
    asm volatile("s_waitcnt vmcnt(0)" ::: "memory");
    __builtin_amdgcn_s_barrier();
    __builtin_amdgcn_sched_barrier(0);

    int cur = 0;
    for (int t = 0; t < nt; ++t) {
        if (t + 1 < nt) STAGE(cur ^ 1, (t + 1) << 5);

        const u16* Ab = &As[cur][0];
        const u16* Bb = &Bs[cur][0];
        s8v af[4], bf[4];
#pragma unroll
        for (int m = 0; m < 4; ++m)
            af[m] = *(const s8v*)&Ab[(wr + m * 16 + li) * 32 + fo];
#pragma unroll
        for (int n = 0; n < 4; ++n)
            bf[n] = *(const s8v*)&Bb[(wc + n * 16 + li) * 32 + fo];
#pragma unroll
        for (int m = 0; m < 4; ++m)
#pragma unroll
            for (int n = 0; n < 4; ++n)
                acc[m][n] = __builtin_amdgcn_mfma_f32_16x16x32_bf16(
                    af[m], bf[n], acc[m][n], 0, 0, 0);

        if (t + 1 < nt) {
            asm volatile("s_waitcnt vmcnt(0)" ::: "memory");
            __builtin_amdgcn_s_barrier();
            __builtin_amdgcn_sched_barrier(0);
            cur ^= 1;
        }
    }
#undef STAGE

#pragma unroll
    for (int m = 0; m < 4; ++m) {
#pragma unroll
        for (int j = 0; j < 4; ++j) {
            int row = bm + wr + m * 16 + kc * 4 + j;
#pragma unroll
            for (int n = 0; n < 4; ++n) {
                int col = bn + wc + n * 16 + li;
                float v = acc[m][n][j];
                C0[(size_t)row * ldc0 + col] = v;
                Cb[(size_t)row * ldc0 + col] = f2bf(v);
            }
        }
    }
}

// ---------------------------------------------------------------- fp32 SGEMM (small ops)
template<int EPI, bool NGUARD, bool SPLITK>
__global__ __launch_bounds__(256) void sgemm_bt(
    const float* __restrict__ A, int lda,
    const float* __restrict__ Bt, int ldb,
    float* __restrict__ C, int ldc,
    const float* __restrict__ bias,
    int M, int N, int K, int kchunk)
{
    __shared__ float As[16][132];
    __shared__ float Bs[16][132];

    const int tid = threadIdx.x;
    const int bm = blockIdx.y * 128;
    const int bn = blockIdx.x * 128;

    int k0 = 0, kend = K;
    if (SPLITK) {
        k0 = blockIdx.z * kchunk;
        kend = k0 + kchunk; if (kend > K) kend = K;
        C += (size_t)blockIdx.z * (size_t)M * (size_t)ldc;
    }

    const int tx = tid & 15;
    const int ty = tid >> 4;
    const int lr = tid >> 2;
    const int lc = (tid & 3) << 2;

    float acc[8][8];
#pragma unroll
    for (int i = 0; i < 8; ++i)
#pragma unroll
        for (int j = 0; j < 8; ++j) acc[i][j] = 0.f;

    for (int kk = k0; kk < kend; kk += 16) {
#pragma unroll
        for (int p = 0; p < 2; ++p) {
            int r = lr + p * 64;
            float4 v = *(const float4*)(A + (size_t)(bm + r) * lda + kk + lc);
            As[lc + 0][r] = v.x; As[lc + 1][r] = v.y;
            As[lc + 2][r] = v.z; As[lc + 3][r] = v.w;
        }
#pragma unroll
        for (int p = 0; p < 2; ++p) {
            int r = lr + p * 64;
            float4 v = make_float4(0.f, 0.f, 0.f, 0.f);
            if (!NGUARD || (bn + r) < N)
                v = *(const float4*)(Bt + (size_t)(bn + r) * ldb + kk + lc);
            Bs[lc + 0][r] = v.x; Bs[lc + 1][r] = v.y;
            Bs[lc + 2][r] = v.z; Bs[lc + 3][r] = v.w;
        }
        __syncthreads();
#pragma unroll
        for (int k = 0; k < 16; ++k) {
            float4 a0 = *(const float4*)&As[k][ty * 4];
            float4 a1 = *(const float4*)&As[k][64 + ty * 4];
            float4 b0 = *(const float4*)&Bs[k][tx * 4];
            float4 b1 = *(const float4*)&Bs[k][64 + tx * 4];
            float av[8] = {a0.x, a0.y, a0.z, a0.w, a1.x, a1.y, a1.z, a1.w};
            float bv[8] = {b0.x, b0.y, b0.z, b0.w, b1.x, b1.y, b1.z, b1.w};
#pragma unroll
            for (int i = 0; i < 8; ++i)
#pragma unroll
                for (int j = 0; j < 8; ++j)
                    acc[i][j] += av[i] * bv[j];
        }
        __syncthreads();
    }

#pragma unroll
    for (int p = 0; p < 2; ++p) {
#pragma unroll
        for (int ii = 0; ii < 4; ++ii) {
            int row = bm + p * 64 + ty * 4 + ii;
#pragma unroll
            for (int q = 0; q < 2; ++q) {
                int col = bn + q * 64 + tx * 4;
                if (NGUARD && col >= N) continue;
                float4 v;
                float* vp = &v.x;
#pragma unroll
                for (int jj = 0; jj < 4; ++jj) {
                    float x = acc[p * 4 + ii][q * 4 + jj];
                    if (EPI == 1) {
                        x += bias[col + jj];
                        x = (x > 20.f) ? x : log1pf(__expf(x));
                    }
                    vp[jj] = x;
                }
                *(float4*)(C + (size_t)row * ldc + col) = v;
            }
        }
    }
}

// ---------------------------------------------------------------- split-K reduce
__global__ __launch_bounds__(256) void reduce8_kernel(
    const float* __restrict__ part, float* __restrict__ out, int n)
{
    int i = blockIdx.x * 256 + threadIdx.x;
    if (i < n) {
        float s = 0.f;
#pragma unroll
        for (int j = 0; j < 8; ++j) s += part[(size_t)j * n + i];
        out[i] = s;
    }
}

// ---------------------------------------------------------------- conv + SiLU
__global__ __launch_bounds__(256) void conv_silu_kernel(
    const float* __restrict__ XZu, const float* __restrict__ cw,
    const float* __restrict__ cb, float* __restrict__ U)
{
    int idx = blockIdx.x * 256 + threadIdx.x;
    int c4 = idx & 511;
    int row = idx >> 9;
    int t = row & (L_SEQ - 1);
    int c = c4 << 2;

    float4 acc;
    acc.x = cb[c]; acc.y = cb[c + 1]; acc.z = cb[c + 2]; acc.w = cb[c + 3];
    float4 w0 = *(const float4*)(cw + (size_t)(c + 0) * 4);
    float4 w1 = *(const float4*)(cw + (size_t)(c + 1) * 4);
    float4 w2 = *(const float4*)(cw + (size_t)(c + 2) * 4);
    float4 w3 = *(const float4*)(cw + (size_t)(c + 3) * 4);
#pragma unroll
    for (int k = 0; k < 4; ++k) {
        int tt = t - 3 + k;
        if (tt >= 0) {
            float4 xv = *(const float4*)(XZu + (size_t)(row - 3 + k) * DI + c);
            acc.x += xv.x * ((&w0.x)[k]);
            acc.y += xv.y * ((&w1.x)[k]);
            acc.z += xv.z * ((&w2.x)[k]);
            acc.w += xv.w * ((&w3.x)[k]);
        }
    }
    acc.x = acc.x / (1.f + __expf(-acc.x));
    acc.y = acc.y / (1.f + __expf(-acc.y));
    acc.z = acc.z / (1.f + __expf(-acc.z));
    acc.w = acc.w / (1.f + __expf(-acc.w));
    *(float4*)(U + (size_t)row * DI + c) = acc;
}

// ---------------------------------------------------------------- fused chunked scan
__global__ __launch_bounds__(256) void scan_fused(
    const float* __restrict__ U, const float* __restrict__ DELTA,
    const float* __restrict__ DBL, const float* __restrict__ ZF,
    const float* __restrict__ A_log, const float* __restrict__ Dskip,
    u16* __restrict__ Yb)
{
    __shared__ float ps[EL][NCH][DS][2];   // 32 KB (P,S)
    __shared__ float hs[EL][NCH][DS];      // 16 KB (h_start)

    const int tid   = threadIdx.x;
    const int el    = tid & (EL - 1);
    const int chunk = tid >> 3;            // 0..31
    const int bid   = blockIdx.x;
    const int b     = bid >> 8;            // DI/EL = 256 e-groups
    const int e     = (bid & 255) * EL + el;
    const int t0    = chunk * CHL;

    float Ae[DS];
#pragma unroll
    for (int s = 0; s < DS; ++s)
        Ae[s] = -__expf(A_log[(size_t)e * DS + s]);

    const float* up = U     + (size_t)b * L_SEQ * DI + e;
    const float* dp = DELTA + (size_t)b * L_SEQ * DI + e;
    const float* zp = ZF    + (size_t)b * L_SEQ * DI + e;
    const float* bp = DBL   + ((size_t)b * L_SEQ + t0) * DBLC + DTR;
    const float* cp = bp + DS;
    u16* yp = Yb + (size_t)b * L_SEQ * DI + e;

    float P[DS], S[DS];
#pragma unroll
    for (int s = 0; s < DS; ++s) { P[s] = 1.f; S[s] = 0.f; }

    {
        float u0 = up[(size_t)t0 * DI];
        float d0 = dp[(size_t)t0 * DI];
        float4 B0[4];
#pragma unroll
        for (int q = 0; q < 4; ++q) B0[q] = *(const float4*)(bp + q * 4);

        for (int i = 0; i < CHL; ++i) {
            float u1 = 0.f, d1 = 0.f;
            float4 B1[4] = {};
            if (i + 1 < CHL) {
                u1 = up[(size_t)(t0 + i + 1) * DI];
                d1 = dp[(size_t)(t0 + i + 1) * DI];
#pragma unroll
                for (int q = 0; q < 4; ++q)
                    B1[q] = *(const float4*)(bp + (i + 1) * DBLC + q * 4);
            }
            float du = d0 * u0;
            const float* Bf = (const float*)&B0[0];
#pragma unroll
            for (int s = 0; s < DS; ++s) {
                float a = __expf(d0 * Ae[s]);
                P[s] *= a;
                S[s] = S[s] * a + du * Bf[s];
            }
            u0 = u1; d0 = d1;
#pragma unroll
            for (int q = 0; q < 4; ++q) B0[q] = B1[q];
        }
    }
#pragma unroll
    for (int s = 0; s < DS; ++s) {
        ps[el][chunk][s][0] = P[s];
        ps[el][chunk][s][1] = S[s];
    }
    __syncthreads();

    if (tid < EL * DS) {
        int pel = tid >> 4;
        int s   = tid & 15;
        float h = 0.f;
#pragma unroll
        for (int c = 0; c < NCH; ++c) {
            hs[pel][c][s] = h;
            h = ps[pel][c][s][0] * h + ps[pel][c][s][1];
        }
    }
    __syncthreads();

    float Dk = Dskip[e];
    float h[DS];
#pragma unroll
    for (int s = 0; s < DS; ++s) h[s] = hs[el][chunk][s];

    {
        float u0 = up[(size_t)t0 * DI];
        float d0 = dp[(size_t)t0 * DI];
        float z0 = zp[(size_t)t0 * DI];
        float4 B0[4], C0[4];
#pragma unroll
        for (int q = 0; q < 4; ++q) {
            B0[q] = *(const float4*)(bp + q * 4);
            C0[q] = *(const float4*)(cp + q * 4);
        }

        for (int i = 0; i < CHL; ++i) {
            float u1 = 0.f, d1 = 0.f, z1 = 0.f;
            float4 B1[4] = {}, C1[4] = {};
            if (i + 1 < CHL) {
                u1 = up[(size_t)(t0 + i + 1) * DI];
                d1 = dp[(size_t)(t0 + i + 1) * DI];
                z1 = zp[(size_t)(t0 + i + 1) * DI];
#pragma unroll
                for (int q = 0; q < 4; ++q) {
                    B1[q] = *(const float4*)(bp + (i + 1) * DBLC + q * 4);
                    C1[q] = *(const float4*)(cp + (i + 1) * DBLC + q * 4);
                }
            }
            float du = d0 * u0;
            const float* Bf = (const float*)&B0[0];
            const float* Cf = (const float*)&C0[0];
            float y0 = 0.f, y1 = 0.f, y2 = 0.f, y3 = 0.f;
#pragma unroll
            for (int s = 0; s < DS; ++s) {
                float a = __expf(d0 * Ae[s]);
                h[s] = h[s] * a + du * Bf[s];
                float hc = h[s] * Cf[s];
                if ((s & 3) == 0) y0 += hc;
                else if ((s & 3) == 1) y1 += hc;
                else if ((s & 3) == 2) y2 += hc;
                else y3 += hc;
            }
            float p = (y0 + y1) + (y2 + y3);
            float g = z0 / (1.f + __expf(-z0));
            yp[(size_t)(t0 + i) * DI] = f2bf((p + u0 * Dk) * g);
            u0 = u1; d0 = d1; z0 = z1;
#pragma unroll
            for (int q = 0; q < 4; ++q) { B0[q] = B1[q]; C0[q] = C1[q]; }
        }
    }
}

// ---------------------------------------------------------------- layernorm (bf16 out)
__global__ __launch_bounds__(256) void layernorm_kernel(
    const float* __restrict__ X, const float* __restrict__ g,
    const float* __restrict__ be, u16* __restrict__ XNb)
{
    __shared__ float red[4];
    int row = blockIdx.x;
    int tid = threadIdx.x;
    float4 v = ((const float4*)(X + (size_t)row * DM))[tid];

    float ssum = v.x + v.y + v.z + v.w;
#pragma unroll
    for (int o = 32; o >= 1; o >>= 1) ssum += __shfl_xor(ssum, o);
    if ((tid & 63) == 0) red[tid >> 6] = ssum;
    __syncthreads();
    float mean = (red[0] + red[1] + red[2] + red[3]) * (1.f / DM);
    __syncthreads();

    float dx = v.x - mean, dy = v.y - mean, dz = v.z - mean, dw = v.w - mean;
    float sq = dx * dx + dy * dy + dz * dz + dw * dw;
#pragma unroll
    for (int o = 32; o >= 1; o >>= 1) sq += __shfl_xor(sq, o);
    if ((tid & 63) == 0) red[tid >> 6] = sq;
    __syncthreads();
    float var = (red[0] + red[1] + red[2] + red[3]) * (1.f / DM);
    float rs = rsqrtf(var + 1e-5f);

    float4 gv = ((const float4*)g)[tid];
    float4 bv = ((const float4*)be)[tid];
    ushort4 o;
    o.x = f2bf(dx * rs * gv.x + bv.x);
    o.y = f2bf(dy * rs * gv.y + bv.y);
    o.z = f2bf(dz * rs * gv.z + bv.z);
    o.w = f2bf(dw * rs * gv.w + bv.w);
    ((ushort4*)(XNb + (size_t)row * DM))[tid] = o;
}

// ---------------------------------------------------------------- launch
extern "C" void kernel_launch(void* const* d_in, const int* in_sizes, int n_in,
                              void* d_out, int out_size, void* d_ws, size_t ws_size,
                              hipStream_t stream)
{
    const int*   tokens = (const int*)d_in[0];
    const float* emb    = (const float*)d_in[1];
    const float* in_w   = (const float*)d_in[2];
    const float* conv_w = (const float*)d_in[3];
    const float* conv_b = (const float*)d_in[4];
    const float* xp_w   = (const float*)d_in[5];
    const float* dt_w   = (const float*)d_in[6];
    const float* dt_b   = (const float*)d_in[7];
    const float* A_log  = (const float*)d_in[8];
    const float* Dskip  = (const float*)d_in[9];
    const float* out_w  = (const float*)d_in[10];
    const float* gamma  = (const float*)d_in[11];
    const float* beta   = (const float*)d_in[12];
    const float* lm_w   = (const float*)d_in[13];
    float* out = (float*)d_out;

    // ---- workspace: 43.39M floats = 173.6 MB (round-4..11-proven size).
    float* ws = (float*)d_ws;
    size_t off = 0;
    float* X     = ws + off; off += (size_t)BL * DM;        //  4.19M  fp32 LN input
    float* XZu   = ws + off; off += (size_t)BL * DI;        //  8.39M
    float* U     = ws + off; off += (size_t)BL * DI;        //  8.39M
    float* ZF    = ws + off; off += (size_t)BL * DI;        //  8.39M
    float* DELTA = ws + off; off += (size_t)BL * DI;        //  8.39M
    float* DBL   = ws + off; off += (size_t)BL * DBLC;      //  0.39M
    u16* Xb     = (u16*)(ws + off); off += (size_t)BL * DM / 2;      // 2.10M
    u16* wb_in  = (u16*)(ws + off); off += (size_t)2 * DI * DM / 2;  // 2.10M
    u16* wb_out = (u16*)(ws + off); off += (size_t)DM * DI / 2;      // 1.05M
    // aliases (lifetime-checked):
    u16* Yb    = (u16*)XZu;   // scan out; XZu dead after conv_silu
    u16* wb_lm = (u16*)XZu;   // over [XZu|U]; dead after layer-2 out_proj
    float* PART = DELTA;      // split-K partials; consumed before dt_proj
    u16* XNb   = Xb;          // LN out; Xb dead after layer-2 in_proj

    embed_kernel<<<BL, 256, 0, stream>>>(tokens, emb, Xb);

    const int SCAN_GRID = BATCH * (DI / EL);  // 512 blocks

    for (int l = 0; l < 2; ++l) {
        const float* cwp = conv_w + (size_t)l * DI * 4;
        const float* cbp = conv_b + (size_t)l * DI;
        const float* xw  = xp_w   + (size_t)l * DBLC * DI;
        const float* dw  = dt_w   + (size_t)l * DI * DTR;
        const float* dbp = dt_b   + (size_t)l * DI;
        const float* alp = A_log  + (size_t)l * DI * DS;
        const float* dkp = Dskip  + (size_t)l * DI;

        const int n8i = 2 * DI * DM / 8, n8o = DM * DI / 8;
        cvt2_bf16_kernel<<<(n8i + n8o + 255) / 256, 256, 0, stream>>>(
            in_w + (size_t)l * 2 * DI * DM, wb_in, n8i,
            out_w + (size_t)l * DM * DI, wb_out, n8o);

        // xz = x @ in_w^T : [4096,4096] K=1024; u-half -> XZu, z-half -> ZF
        gemm_deep<1><<<dim3(16, 16), 512, 0, stream>>>(
            Xb, DM, wb_in, DM, XZu, ZF, 0, DM);
        // u = silu(conv(XZu))
        conv_silu_kernel<<<(BL * DI / 4) / 256, 256, 0, stream>>>(XZu, cwp, cbp, U);
        // x_dbl = u @ xp_w^T : [4096,96] fp32 split-K
        sgemm_bt<0, true, true><<<dim3(1, 32, 8), 256, 0, stream>>>(
            U, DI, xw, DI, PART, DBLC, nullptr, BL, DBLC, DI, DI / 8);
        reduce8_kernel<<<(BL * DBLC + 255) / 256, 256, 0, stream>>>(
            PART, DBL, BL * DBLC);
        // delta = softplus(dt @ dt_w^T + dt_b) fp32 (K=64)
        sgemm_bt<1, false, false><<<dim3(16, 32), 256, 0, stream>>>(
            DBL, DBLC, dw, DTR, DELTA, DI, dbp, BL, DI, DTR, 0);
        // fused chunked scan -> bf16 Yb (aliases XZu)
        scan_fused<<<SCAN_GRID, 256, 0, stream>>>(
            U, DELTA, DBL, ZF, alp, dkp, Yb);
        // x = y @ out_w^T : [4096,1024] K=2048 (128^2 2-phase, 256 blocks)
        gemm_bb2<<<dim3(32, 8), 256, 0, stream>>>(
            Yb, DI, wb_out, DI, X, Xb, DM, DI);
    }

    cvt_bf16_kernel<<<((size_t)VOCAB * DM / 8 + 255) / 256, 256, 0, stream>>>(
        lm_w, wb_lm, VOCAB * DM / 8);

    layernorm_kernel<<<BL, 256, 0, stream>>>(X, gamma, beta, XNb);

    // logits = xn @ lm_head^T : [4096,32000] K=1024 (deep pipeline)
    gemm_deep<0><<<dim3(16, 125), 512, 0, stream>>>(
        XNb, DM, wb_lm, DM, out, nullptr, VOCAB, DM);
}

// Round 13
// 1033.257 us; speedup vs baseline: 1.0710x; 1.0710x over previous
//
#include <hip/hip_runtime.h>
#include <hip/hip_bf16.h>

#define L_SEQ 2048
#define BATCH 2
#define DM    1024          // d_model
#define DI    2048          // d_inner
#define DS    16            // d_state
#define DTR   64            // dt_rank
#define DBLC  96            // dt_rank + 2*d_state
#define VOCAB 32000
#define BL    (BATCH * L_SEQ)   // 4096 tokens
#define NCH   32            // scan chunks
#define CHL   (L_SEQ / NCH) // 64 steps per chunk
#define EL    8             // channels per scan block

typedef unsigned short u16;
typedef short s8v  __attribute__((ext_vector_type(8)));   // 8 bf16
typedef float f32x4 __attribute__((ext_vector_type(4)));

typedef __attribute__((address_space(1))) const void* as1cv;
typedef __attribute__((address_space(3))) void*       as3v;

// round-to-nearest-even fp32 -> bf16
static __device__ __forceinline__ u16 f2bf(float f) {
    unsigned u = __builtin_bit_cast(unsigned, f);
    u += 0x7fffu + ((u >> 16) & 1u);
    return (u16)(u >> 16);
}

// ---------------------------------------------------------------- fp32 -> bf16 converts
__global__ __launch_bounds__(256) void cvt_bf16_kernel(
    const float* __restrict__ in, u16* __restrict__ out, int n8)
{
    int i = blockIdx.x * 256 + threadIdx.x;
    if (i >= n8) return;
    const float4* p = (const float4*)in + 2 * (size_t)i;
    float4 a = p[0], b = p[1];
    s8v o;
    o[0] = (short)f2bf(a.x); o[1] = (short)f2bf(a.y);
    o[2] = (short)f2bf(a.z); o[3] = (short)f2bf(a.w);
    o[4] = (short)f2bf(b.x); o[5] = (short)f2bf(b.y);
    o[6] = (short)f2bf(b.z); o[7] = (short)f2bf(b.w);
    ((s8v*)out)[i] = o;
}

// two tensors in one dispatch (per-layer in_w + out_w)
__global__ __launch_bounds__(256) void cvt2_bf16_kernel(
    const float* __restrict__ inA, u16* __restrict__ outA, int n8A,
    const float* __restrict__ inB, u16* __restrict__ outB, int n8B)
{
    int i = blockIdx.x * 256 + threadIdx.x;
    const float* src; u16* dst; int idx;
    if (i < n8A) { src = inA; dst = outA; idx = i; }
    else if (i < n8A + n8B) { src = inB; dst = outB; idx = i - n8A; }
    else return;
    const float4* p = (const float4*)src + 2 * (size_t)idx;
    float4 a = p[0], b = p[1];
    s8v o;
    o[0] = (short)f2bf(a.x); o[1] = (short)f2bf(a.y);
    o[2] = (short)f2bf(a.z); o[3] = (short)f2bf(a.w);
    o[4] = (short)f2bf(b.x); o[5] = (short)f2bf(b.y);
    o[6] = (short)f2bf(b.z); o[7] = (short)f2bf(b.w);
    ((s8v*)dst)[idx] = o;
}

// ---------------------------------------------------------------- embedding (bf16 out)
__global__ __launch_bounds__(256) void embed_kernel(
    const int* __restrict__ tok, const float* __restrict__ emb,
    u16* __restrict__ Xb)
{
    int row = blockIdx.x;
    int t = tok[row];
    float4 v = ((const float4*)(emb + (size_t)t * DM))[threadIdx.x];
    ushort4 o;
    o.x = f2bf(v.x); o.y = f2bf(v.y); o.z = f2bf(v.z); o.w = f2bf(v.w);
    ((ushort4*)(Xb + (size_t)row * DM))[threadIdx.x] = o;
}

// ---------------------------------------------------------------- bf16 MFMA GEMM
// C = A[M,K](bf16) * Bt[N,K](bf16)^T.  128x128 tile, BK=32, 256 thr = 4
// waves (2x2), wave tile 64x64 = 4x4 x mfma_f32_16x16x32_bf16.
// EMPIRICAL OPTIMUM of this session's structure space (round 8, 1032 us):
// 2-buffer, prefetch-before-compute, one vmcnt(0)+s_barrier per K-step,
// ~3.5 blocks/CU. All deeper variants lost (r9-r12: counted-vmcnt 3-buf,
// 256x128, 256^2 4-buf deep) — inter-block TLP is the dominant
// latency-hiding mechanism here; LDS growth that cuts blocks/CU loses more
// than pipeline depth gains. XOR slot-swizzle both-sides (rule #21).
// MODE 0: fp32 C0.  MODE 1: in_proj split u/z.  MODE 2: fp32 C0 + bf16 Cb.
template<int MODE>
__global__ __launch_bounds__(256) void gemm_bb(
    const u16* __restrict__ A, int lda,
    const u16* __restrict__ Bt, int ldb,
    float* __restrict__ C0, float* __restrict__ C1,
    u16* __restrict__ Cb, int ldc0, int K)
{
    __shared__ __align__(16) u16 As[2][128 * 32];
    __shared__ __align__(16) u16 Bs[2][128 * 32];

    const int tid  = threadIdx.x;
    const int lane = tid & 63;
    const int wv   = tid >> 6;
    const int bm = blockIdx.x * 128;
    const int bn = blockIdx.y * 128;

    const int ks = (lane & 3) ^ ((lane >> 3) & 3);
    const int sr = wv * 32 + (lane >> 2);
    const u16* ag0 = A  + (size_t)(bm + sr) * lda + ks * 8;
    const u16* ag1 = ag0 + 16 * (size_t)lda;
    const u16* bg0 = Bt + (size_t)(bn + sr) * ldb + ks * 8;
    const u16* bg1 = bg0 + 16 * (size_t)ldb;
    const int lo0 = wv * 1024;
    const int lo1 = wv * 1024 + 512;

    const int li = lane & 15;
    const int kc = lane >> 4;
    const int wr = (wv >> 1) * 64;
    const int wc = (wv & 1) * 64;
    const int fo = (kc ^ ((li >> 1) & 3)) * 8;

    f32x4 acc[4][4];
#pragma unroll
    for (int m = 0; m < 4; ++m)
#pragma unroll
        for (int n = 0; n < 4; ++n) acc[m][n] = (f32x4)0.f;

#define STAGE(buf, kk)                                                         \
    do {                                                                       \
        __builtin_amdgcn_global_load_lds((as1cv)(ag0 + (kk)),                  \
            (as3v)&As[buf][lo0], 16, 0, 0);                                    \
        __builtin_amdgcn_global_load_lds((as1cv)(ag1 + (kk)),                  \
            (as3v)&As[buf][lo1], 16, 0, 0);                                    \
        __builtin_amdgcn_global_load_lds((as1cv)(bg0 + (kk)),                  \
            (as3v)&Bs[buf][lo0], 16, 0, 0);                                    \
        __builtin_amdgcn_global_load_lds((as1cv)(bg1 + (kk)),                  \
            (as3v)&Bs[buf][lo1], 16, 0, 0);                                    \
    } while (0)

    const int nt = K >> 5;    // K/32 tiles
    STAGE(0, 0);
    asm volatile("s_waitcnt vmcnt(0)" ::: "memory");
    __builtin_amdgcn_s_barrier();
    __builtin_amdgcn_sched_barrier(0);

    int cur = 0;
    for (int t = 0; t < nt; ++t) {
        if (t + 1 < nt) STAGE(cur ^ 1, (t + 1) << 5);   // prefetch next tile

        const u16* Ab = &As[cur][0];
        const u16* Bb = &Bs[cur][0];
        s8v af[4], bf[4];
#pragma unroll
        for (int m = 0; m < 4; ++m)
            af[m] = *(const s8v*)&Ab[(wr + m * 16 + li) * 32 + fo];
#pragma unroll
        for (int n = 0; n < 4; ++n)
            bf[n] = *(const s8v*)&Bb[(wc + n * 16 + li) * 32 + fo];
#pragma unroll
        for (int m = 0; m < 4; ++m)
#pragma unroll
            for (int n = 0; n < 4; ++n)
                acc[m][n] = __builtin_amdgcn_mfma_f32_16x16x32_bf16(
                    af[m], bf[n], acc[m][n], 0, 0, 0);

        if (t + 1 < nt) {
            asm volatile("s_waitcnt vmcnt(0)" ::: "memory");
            __builtin_amdgcn_s_barrier();
            __builtin_amdgcn_sched_barrier(0);
            cur ^= 1;
        }
    }
#undef STAGE

    // C row = bm+wr+m*16+kc*4+j, col = bn+wc+n*16+li
#pragma unroll
    for (int m = 0; m < 4; ++m) {
#pragma unroll
        for (int j = 0; j < 4; ++j) {
            int row = bm + wr + m * 16 + kc * 4 + j;
#pragma unroll
            for (int n = 0; n < 4; ++n) {
                int col = bn + wc + n * 16 + li;
                float v = acc[m][n][j];
                if (MODE == 0) {
                    C0[(size_t)row * ldc0 + col] = v;
                } else if (MODE == 1) {
                    if (bn < DI) C0[(size_t)row * DI + col] = v;
                    else         C1[(size_t)row * DI + col - DI] = v;
                } else {
                    C0[(size_t)row * ldc0 + col] = v;
                    Cb[(size_t)row * ldc0 + col] = f2bf(v);
                }
            }
        }
    }
}

// ---------------------------------------------------------------- fp32 SGEMM (small ops)
template<int EPI, bool NGUARD, bool SPLITK>
__global__ __launch_bounds__(256) void sgemm_bt(
    const float* __restrict__ A, int lda,
    const float* __restrict__ Bt, int ldb,
    float* __restrict__ C, int ldc,
    const float* __restrict__ bias,
    int M, int N, int K, int kchunk)
{
    __shared__ float As[16][132];
    __shared__ float Bs[16][132];

    const int tid = threadIdx.x;
    const int bm = blockIdx.y * 128;
    const int bn = blockIdx.x * 128;

    int k0 = 0, kend = K;
    if (SPLITK) {
        k0 = blockIdx.z * kchunk;
        kend = k0 + kchunk; if (kend > K) kend = K;
        C += (size_t)blockIdx.z * (size_t)M * (size_t)ldc;
    }

    const int tx = tid & 15;
    const int ty = tid >> 4;
    const int lr = tid >> 2;
    const int lc = (tid & 3) << 2;

    float acc[8][8];
#pragma unroll
    for (int i = 0; i < 8; ++i)
#pragma unroll
        for (int j = 0; j < 8; ++j) acc[i][j] = 0.f;

    for (int kk = k0; kk < kend; kk += 16) {
#pragma unroll
        for (int p = 0; p < 2; ++p) {
            int r = lr + p * 64;
            float4 v = *(const float4*)(A + (size_t)(bm + r) * lda + kk + lc);
            As[lc + 0][r] = v.x; As[lc + 1][r] = v.y;
            As[lc + 2][r] = v.z; As[lc + 3][r] = v.w;
        }
#pragma unroll
        for (int p = 0; p < 2; ++p) {
            int r = lr + p * 64;
            float4 v = make_float4(0.f, 0.f, 0.f, 0.f);
            if (!NGUARD || (bn + r) < N)
                v = *(const float4*)(Bt + (size_t)(bn + r) * ldb + kk + lc);
            Bs[lc + 0][r] = v.x; Bs[lc + 1][r] = v.y;
            Bs[lc + 2][r] = v.z; Bs[lc + 3][r] = v.w;
        }
        __syncthreads();
#pragma unroll
        for (int k = 0; k < 16; ++k) {
            float4 a0 = *(const float4*)&As[k][ty * 4];
            float4 a1 = *(const float4*)&As[k][64 + ty * 4];
            float4 b0 = *(const float4*)&Bs[k][tx * 4];
            float4 b1 = *(const float4*)&Bs[k][64 + tx * 4];
            float av[8] = {a0.x, a0.y, a0.z, a0.w, a1.x, a1.y, a1.z, a1.w};
            float bv[8] = {b0.x, b0.y, b0.z, b0.w, b1.x, b1.y, b1.z, b1.w};
#pragma unroll
            for (int i = 0; i < 8; ++i)
#pragma unroll
                for (int j = 0; j < 8; ++j)
                    acc[i][j] += av[i] * bv[j];
        }
        __syncthreads();
    }

#pragma unroll
    for (int p = 0; p < 2; ++p) {
#pragma unroll
        for (int ii = 0; ii < 4; ++ii) {
            int row = bm + p * 64 + ty * 4 + ii;
#pragma unroll
            for (int q = 0; q < 2; ++q) {
                int col = bn + q * 64 + tx * 4;
                if (NGUARD && col >= N) continue;
                float4 v;
                float* vp = &v.x;
#pragma unroll
                for (int jj = 0; jj < 4; ++jj) {
                    float x = acc[p * 4 + ii][q * 4 + jj];
                    if (EPI == 1) {
                        x += bias[col + jj];
                        x = (x > 20.f) ? x : log1pf(__expf(x));
                    }
                    vp[jj] = x;
                }
                *(float4*)(C + (size_t)row * ldc + col) = v;
            }
        }
    }
}

// ---------------------------------------------------------------- split-K reduce
__global__ __launch_bounds__(256) void reduce8_kernel(
    const float* __restrict__ part, float* __restrict__ out, int n)
{
    int i = blockIdx.x * 256 + threadIdx.x;
    if (i < n) {
        float s = 0.f;
#pragma unroll
        for (int j = 0; j < 8; ++j) s += part[(size_t)j * n + i];
        out[i] = s;
    }
}

// ---------------------------------------------------------------- conv + SiLU
__global__ __launch_bounds__(256) void conv_silu_kernel(
    const float* __restrict__ XZu, const float* __restrict__ cw,
    const float* __restrict__ cb, float* __restrict__ U)
{
    int idx = blockIdx.x * 256 + threadIdx.x;
    int c4 = idx & 511;
    int row = idx >> 9;
    int t = row & (L_SEQ - 1);
    int c = c4 << 2;

    float4 acc;
    acc.x = cb[c]; acc.y = cb[c + 1]; acc.z = cb[c + 2]; acc.w = cb[c + 3];
    float4 w0 = *(const float4*)(cw + (size_t)(c + 0) * 4);
    float4 w1 = *(const float4*)(cw + (size_t)(c + 1) * 4);
    float4 w2 = *(const float4*)(cw + (size_t)(c + 2) * 4);
    float4 w3 = *(const float4*)(cw + (size_t)(c + 3) * 4);
#pragma unroll
    for (int k = 0; k < 4; ++k) {
        int tt = t - 3 + k;
        if (tt >= 0) {
            float4 xv = *(const float4*)(XZu + (size_t)(row - 3 + k) * DI + c);
            acc.x += xv.x * ((&w0.x)[k]);
            acc.y += xv.y * ((&w1.x)[k]);
            acc.z += xv.z * ((&w2.x)[k]);
            acc.w += xv.w * ((&w3.x)[k]);
        }
    }
    acc.x = acc.x / (1.f + __expf(-acc.x));
    acc.y = acc.y / (1.f + __expf(-acc.y));
    acc.z = acc.z / (1.f + __expf(-acc.z));
    acc.w = acc.w / (1.f + __expf(-acc.w));
    *(float4*)(U + (size_t)row * DI + c) = acc;
}

// ---------------------------------------------------------------- fused chunked scan
// h_t = a_t h_{t-1} + b_t ; a_t = exp(d_t*A), b_t = d_t u_t B_t ; y = <h,C>.
// thread = (e, chunk), DS=16 states in registers; block = 8e x 32chunks;
// in-LDS chunk prefix between barriers (all passes fused).
__global__ __launch_bounds__(256) void scan_fused(
    const float* __restrict__ U, const float* __restrict__ DELTA,
    const float* __restrict__ DBL, const float* __restrict__ ZF,
    const float* __restrict__ A_log, const float* __restrict__ Dskip,
    u16* __restrict__ Yb)
{
    __shared__ float ps[EL][NCH][DS][2];   // 32 KB (P,S)
    __shared__ float hs[EL][NCH][DS];      // 16 KB (h_start)

    const int tid   = threadIdx.x;
    const int el    = tid & (EL - 1);
    const int chunk = tid >> 3;            // 0..31
    const int bid   = blockIdx.x;
    const int b     = bid >> 8;            // DI/EL = 256 e-groups
    const int e     = (bid & 255) * EL + el;
    const int t0    = chunk * CHL;

    float Ae[DS];
#pragma unroll
    for (int s = 0; s < DS; ++s)
        Ae[s] = -__expf(A_log[(size_t)e * DS + s]);

    const float* up = U     + (size_t)b * L_SEQ * DI + e;
    const float* dp = DELTA + (size_t)b * L_SEQ * DI + e;
    const float* zp = ZF    + (size_t)b * L_SEQ * DI + e;
    const float* bp = DBL   + ((size_t)b * L_SEQ + t0) * DBLC + DTR;
    const float* cp = bp + DS;
    u16* yp = Yb + (size_t)b * L_SEQ * DI + e;

    // ---- phase A: per-chunk transfer function (P, S) per state
    float P[DS], S[DS];
#pragma unroll
    for (int s = 0; s < DS; ++s) { P[s] = 1.f; S[s] = 0.f; }

    {
        float u0 = up[(size_t)t0 * DI];
        float d0 = dp[(size_t)t0 * DI];
        float4 B0[4];
#pragma unroll
        for (int q = 0; q < 4; ++q) B0[q] = *(const float4*)(bp + q * 4);

        for (int i = 0; i < CHL; ++i) {
            float u1 = 0.f, d1 = 0.f;
            float4 B1[4] = {};
            if (i + 1 < CHL) {
                u1 = up[(size_t)(t0 + i + 1) * DI];
                d1 = dp[(size_t)(t0 + i + 1) * DI];
#pragma unroll
                for (int q = 0; q < 4; ++q)
                    B1[q] = *(const float4*)(bp + (i + 1) * DBLC + q * 4);
            }
            float du = d0 * u0;
            const float* Bf = (const float*)&B0[0];
#pragma unroll
            for (int s = 0; s < DS; ++s) {
                float a = __expf(d0 * Ae[s]);
                P[s] *= a;
                S[s] = S[s] * a + du * Bf[s];
            }
            u0 = u1; d0 = d1;
#pragma unroll
            for (int q = 0; q < 4; ++q) B0[q] = B1[q];
        }
    }
#pragma unroll
    for (int s = 0; s < DS; ++s) {
        ps[el][chunk][s][0] = P[s];
        ps[el][chunk][s][1] = S[s];
    }
    __syncthreads();

    // ---- phase B: in-LDS chunk prefix (same order as serial combine)
    if (tid < EL * DS) {
        int pel = tid >> 4;
        int s   = tid & 15;
        float h = 0.f;
#pragma unroll
        for (int c = 0; c < NCH; ++c) {
            hs[pel][c][s] = h;
            h = ps[pel][c][s][0] * h + ps[pel][c][s][1];
        }
    }
    __syncthreads();

    // ---- phase C: rescan from h_start, emit gated bf16 y
    float Dk = Dskip[e];
    float h[DS];
#pragma unroll
    for (int s = 0; s < DS; ++s) h[s] = hs[el][chunk][s];

    {
        float u0 = up[(size_t)t0 * DI];
        float d0 = dp[(size_t)t0 * DI];
        float z0 = zp[(size_t)t0 * DI];
        float4 B0[4], C0[4];
#pragma unroll
        for (int q = 0; q < 4; ++q) {
            B0[q] = *(const float4*)(bp + q * 4);
            C0[q] = *(const float4*)(cp + q * 4);
        }

        for (int i = 0; i < CHL; ++i) {
            float u1 = 0.f, d1 = 0.f, z1 = 0.f;
            float4 B1[4] = {}, C1[4] = {};
            if (i + 1 < CHL) {
                u1 = up[(size_t)(t0 + i + 1) * DI];
                d1 = dp[(size_t)(t0 + i + 1) * DI];
                z1 = zp[(size_t)(t0 + i + 1) * DI];
#pragma unroll
                for (int q = 0; q < 4; ++q) {
                    B1[q] = *(const float4*)(bp + (i + 1) * DBLC + q * 4);
                    C1[q] = *(const float4*)(cp + (i + 1) * DBLC + q * 4);
                }
            }
            float du = d0 * u0;
            const float* Bf = (const float*)&B0[0];
            const float* Cf = (const float*)&C0[0];
            float y0 = 0.f, y1 = 0.f, y2 = 0.f, y3 = 0.f;
#pragma unroll
            for (int s = 0; s < DS; ++s) {
                float a = __expf(d0 * Ae[s]);
                h[s] = h[s] * a + du * Bf[s];
                float hc = h[s] * Cf[s];
                if ((s & 3) == 0) y0 += hc;
                else if ((s & 3) == 1) y1 += hc;
                else if ((s & 3) == 2) y2 += hc;
                else y3 += hc;
            }
            float p = (y0 + y1) + (y2 + y3);
            float g = z0 / (1.f + __expf(-z0));
            yp[(size_t)(t0 + i) * DI] = f2bf((p + u0 * Dk) * g);
            u0 = u1; d0 = d1; z0 = z1;
#pragma unroll
            for (int q = 0; q < 4; ++q) { B0[q] = B1[q]; C0[q] = C1[q]; }
        }
    }
}

// ---------------------------------------------------------------- layernorm (bf16 out)
__global__ __launch_bounds__(256) void layernorm_kernel(
    const float* __restrict__ X, const float* __restrict__ g,
    const float* __restrict__ be, u16* __restrict__ XNb)
{
    __shared__ float red[4];
    int row = blockIdx.x;
    int tid = threadIdx.x;
    float4 v = ((const float4*)(X + (size_t)row * DM))[tid];

    float ssum = v.x + v.y + v.z + v.w;
#pragma unroll
    for (int o = 32; o >= 1; o >>= 1) ssum += __shfl_xor(ssum, o);
    if ((tid & 63) == 0) red[tid >> 6] = ssum;
    __syncthreads();
    float mean = (red[0] + red[1] + red[2] + red[3]) * (1.f / DM);
    __syncthreads();

    float dx = v.x - mean, dy = v.y - mean, dz = v.z - mean, dw = v.w - mean;
    float sq = dx * dx + dy * dy + dz * dz + dw * dw;
#pragma unroll
    for (int o = 32; o >= 1; o >>= 1) sq += __shfl_xor(sq, o);
    if ((tid & 63) == 0) red[tid >> 6] = sq;
    __syncthreads();
    float var = (red[0] + red[1] + red[2] + red[3]) * (1.f / DM);
    float rs = rsqrtf(var + 1e-5f);

    float4 gv = ((const float4*)g)[tid];
    float4 bv = ((const float4*)be)[tid];
    ushort4 o;
    o.x = f2bf(dx * rs * gv.x + bv.x);
    o.y = f2bf(dy * rs * gv.y + bv.y);
    o.z = f2bf(dz * rs * gv.z + bv.z);
    o.w = f2bf(dw * rs * gv.w + bv.w);
    ((ushort4*)(XNb + (size_t)row * DM))[tid] = o;
}

// ---------------------------------------------------------------- launch
extern "C" void kernel_launch(void* const* d_in, const int* in_sizes, int n_in,
                              void* d_out, int out_size, void* d_ws, size_t ws_size,
                              hipStream_t stream)
{
    const int*   tokens = (const int*)d_in[0];
    const float* emb    = (const float*)d_in[1];
    const float* in_w   = (const float*)d_in[2];
    const float* conv_w = (const float*)d_in[3];
    const float* conv_b = (const float*)d_in[4];
    const float* xp_w   = (const float*)d_in[5];
    const float* dt_w   = (const float*)d_in[6];
    const float* dt_b   = (const float*)d_in[7];
    const float* A_log  = (const float*)d_in[8];
    const float* Dskip  = (const float*)d_in[9];
    const float* out_w  = (const float*)d_in[10];
    const float* gamma  = (const float*)d_in[11];
    const float* beta   = (const float*)d_in[12];
    const float* lm_w   = (const float*)d_in[13];
    float* out = (float*)d_out;

    // ---- workspace: 43.39M floats = 173.6 MB (round-4..12-proven size).
    float* ws = (float*)d_ws;
    size_t off = 0;
    float* X     = ws + off; off += (size_t)BL * DM;        //  4.19M  fp32 LN input
    float* XZu   = ws + off; off += (size_t)BL * DI;        //  8.39M
    float* U     = ws + off; off += (size_t)BL * DI;        //  8.39M
    float* ZF    = ws + off; off += (size_t)BL * DI;        //  8.39M
    float* DELTA = ws + off; off += (size_t)BL * DI;        //  8.39M
    float* DBL   = ws + off; off += (size_t)BL * DBLC;      //  0.39M
    u16* Xb     = (u16*)(ws + off); off += (size_t)BL * DM / 2;      // 2.10M
    u16* wb_in  = (u16*)(ws + off); off += (size_t)2 * DI * DM / 2;  // 2.10M
    u16* wb_out = (u16*)(ws + off); off += (size_t)DM * DI / 2;      // 1.05M
    // aliases (lifetime-checked):
    u16* Yb    = (u16*)XZu;   // scan out; XZu dead after conv_silu
    u16* wb_lm = (u16*)XZu;   // over [XZu|U]; dead after layer-2 out_proj
    float* PART = DELTA;      // split-K partials; consumed before dt_proj
    u16* XNb   = Xb;          // LN out; Xb dead after layer-2 in_proj

    embed_kernel<<<BL, 256, 0, stream>>>(tokens, emb, Xb);

    const int SCAN_GRID = BATCH * (DI / EL);  // 512 blocks

    for (int l = 0; l < 2; ++l) {
        const float* cwp = conv_w + (size_t)l * DI * 4;
        const float* cbp = conv_b + (size_t)l * DI;
        const float* xw  = xp_w   + (size_t)l * DBLC * DI;
        const float* dw  = dt_w   + (size_t)l * DI * DTR;
        const float* dbp = dt_b   + (size_t)l * DI;
        const float* alp = A_log  + (size_t)l * DI * DS;
        const float* dkp = Dskip  + (size_t)l * DI;

        // both weight converts in one dispatch
        const int n8i = 2 * DI * DM / 8, n8o = DM * DI / 8;
        cvt2_bf16_kernel<<<(n8i + n8o + 255) / 256, 256, 0, stream>>>(
            in_w + (size_t)l * 2 * DI * DM, wb_in, n8i,
            out_w + (size_t)l * DM * DI, wb_out, n8o);

        // xz = x @ in_w^T : [4096,4096] K=1024; u-half -> XZu, z-half -> ZF
        gemm_bb<1><<<dim3(32, 32), 256, 0, stream>>>(
            Xb, DM, wb_in, DM, XZu, ZF, nullptr, 0, DM);
        // u = silu(conv(XZu))
        conv_silu_kernel<<<(BL * DI / 4) / 256, 256, 0, stream>>>(XZu, cwp, cbp, U);
        // x_dbl = u @ xp_w^T : [4096,96] fp32 split-K
        sgemm_bt<0, true, true><<<dim3(1, 32, 8), 256, 0, stream>>>(
            U, DI, xw, DI, PART, DBLC, nullptr, BL, DBLC, DI, DI / 8);
        reduce8_kernel<<<(BL * DBLC + 255) / 256, 256, 0, stream>>>(
            PART, DBL, BL * DBLC);
        // delta = softplus(dt @ dt_w^T + dt_b) fp32 (K=64)
        sgemm_bt<1, false, false><<<dim3(16, 32), 256, 0, stream>>>(
            DBL, DBLC, dw, DTR, DELTA, DI, dbp, BL, DI, DTR, 0);
        // fused chunked scan -> bf16 Yb (aliases XZu)
        scan_fused<<<SCAN_GRID, 256, 0, stream>>>(
            U, DELTA, DBL, ZF, alp, dkp, Yb);
        // x = y @ out_w^T : [4096,1024] K=2048
        gemm_bb<2><<<dim3(32, 8), 256, 0, stream>>>(
            Yb, DI, wb_out, DI, X, nullptr, Xb, DM, DI);
    }

    cvt_bf16_kernel<<<((size_t)VOCAB * DM / 8 + 255) / 256, 256, 0, stream>>>(
        lm_w, wb_lm, VOCAB * DM / 8);

    layernorm_kernel<<<BL, 256, 0, stream>>>(X, gamma, beta, XNb);

    // logits = xn @ lm_head^T : [4096,32000] K=1024
    gemm_bb<0><<<dim3(32, 250), 256, 0, stream>>>(
        XNb, DM, wb_lm, DM, out, nullptr, nullptr, VOCAB, DM);
}

// Round 14
// 1004.403 us; speedup vs baseline: 1.1018x; 1.0287x over previous
//
#include <hip/hip_runtime.h>
#include <hip/hip_bf16.h>

#define L_SEQ 2048
#define BATCH 2
#define DM    1024          // d_model
#define DI    2048          // d_inner
#define DS    16            // d_state
#define DTR   64            // dt_rank
#define DBLC  96            // dt_rank + 2*d_state
#define VOCAB 32000
#define BL    (BATCH * L_SEQ)   // 4096 tokens
#define NCH   32            // scan chunks
#define CHL   (L_SEQ / NCH) // 64 steps per chunk
#define EL    8             // channels per scan block

typedef unsigned short u16;
typedef short s8v  __attribute__((ext_vector_type(8)));   // 8 bf16
typedef float f32x4 __attribute__((ext_vector_type(4)));

typedef __attribute__((address_space(1))) const void* as1cv;
typedef __attribute__((address_space(3))) void*       as3v;

// round-to-nearest-even fp32 -> bf16
static __device__ __forceinline__ u16 f2bf(float f) {
    unsigned u = __builtin_bit_cast(unsigned, f);
    u += 0x7fffu + ((u >> 16) & 1u);
    return (u16)(u >> 16);
}

// ---------------------------------------------------------------- fp32 -> bf16 converts
__global__ __launch_bounds__(256) void cvt_bf16_kernel(
    const float* __restrict__ in, u16* __restrict__ out, int n8)
{
    int i = blockIdx.x * 256 + threadIdx.x;
    if (i >= n8) return;
    const float4* p = (const float4*)in + 2 * (size_t)i;
    float4 a = p[0], b = p[1];
    s8v o;
    o[0] = (short)f2bf(a.x); o[1] = (short)f2bf(a.y);
    o[2] = (short)f2bf(a.z); o[3] = (short)f2bf(a.w);
    o[4] = (short)f2bf(b.x); o[5] = (short)f2bf(b.y);
    o[6] = (short)f2bf(b.z); o[7] = (short)f2bf(b.w);
    ((s8v*)out)[i] = o;
}

// two tensors in one dispatch (per-layer in_w + out_w)
__global__ __launch_bounds__(256) void cvt2_bf16_kernel(
    const float* __restrict__ inA, u16* __restrict__ outA, int n8A,
    const float* __restrict__ inB, u16* __restrict__ outB, int n8B)
{
    int i = blockIdx.x * 256 + threadIdx.x;
    const float* src; u16* dst; int idx;
    if (i < n8A) { src = inA; dst = outA; idx = i; }
    else if (i < n8A + n8B) { src = inB; dst = outB; idx = i - n8A; }
    else return;
    const float4* p = (const float4*)src + 2 * (size_t)idx;
    float4 a = p[0], b = p[1];
    s8v o;
    o[0] = (short)f2bf(a.x); o[1] = (short)f2bf(a.y);
    o[2] = (short)f2bf(a.z); o[3] = (short)f2bf(a.w);
    o[4] = (short)f2bf(b.x); o[5] = (short)f2bf(b.y);
    o[6] = (short)f2bf(b.z); o[7] = (short)f2bf(b.w);
    ((s8v*)dst)[idx] = o;
}

// ---------------------------------------------------------------- embedding (bf16 out)
__global__ __launch_bounds__(256) void embed_kernel(
    const int* __restrict__ tok, const float* __restrict__ emb,
    u16* __restrict__ Xb)
{
    int row = blockIdx.x;
    int t = tok[row];
    float4 v = ((const float4*)(emb + (size_t)t * DM))[threadIdx.x];
    ushort4 o;
    o.x = f2bf(v.x); o.y = f2bf(v.y); o.z = f2bf(v.z); o.w = f2bf(v.w);
    ((ushort4*)(Xb + (size_t)row * DM))[threadIdx.x] = o;
}

// ---------------------------------------------------------------- 8-phase-style GEMM
// C = A[M,K](bf16) * Bt[N,K](bf16)^T.  256x256 tile, BK=64 (2 K-halves),
// 512 thr = 8 waves (2M x 4N), per-wave 128x64 = 8m x 4n frags.
// PER-PHASE INTERLEAVE (the m196/m201 lever my r9-r12 coarse variants
// missed): 4 phases per K-tile, each = {ds_read one fragment subtile ||
// stage ONE half-tile of t+1 into the other dbuf || barrier || lgkmcnt(0)
// || setprio(1) 16 MFMA setprio(0) || [vmcnt] barrier}.
// LDS: [dbuf][khalf] regions of [256 rows][32 k] for A and B = 128 KB.
//
// HAZARD PROOF:
//  W1 (stage-over-read): stage at t.Pp targets region (d^1, kh) whose last
//     readers ran at tile t-1: kh0 read in (t-1).P1-P2, kh1 in (t-1).P3-P4;
//     each reader's lgkmcnt(0) (data in regs) precedes that phase's end
//     barrier, which precedes t.Pp's stage issue.  -> safe.
//  W2 (read-before-land): P1/P2 read kh0(t), staged at (t-1).P1/P2; the
//     (t-1).P4 vmcnt(4) leaves only (t-1).P3/P4's 4 loads outstanding ->
//     kh0(t) landed; barrier after the wait publishes across waves.
//     P3/P4 read kh1(t), staged (t-1).P3/P4; t.P2's vmcnt(4) leaves only
//     t.P1/P2's 4 loads outstanding -> kh1(t) landed.  Last tile uses
//     vmcnt(0) at P2 (nothing else in flight).
// Accumulation k-order per C element identical to the 2-phase kernel
// (sequential kslots) -> bit-identical results.
// MODE 0: fp32 C0 (ldc0).  MODE 1: in_proj split u/z (C0, C1, ld=DI).
template<int MODE>
__global__ __launch_bounds__(512) void gemm_8p(
    const u16* __restrict__ A, int lda,
    const u16* __restrict__ Bt, int ldb,
    float* __restrict__ C0, float* __restrict__ C1,
    int ldc0, int K)
{
    __shared__ __align__(16) u16 As[4][256 * 32];   // [dbuf*2+kh]  64 KB
    __shared__ __align__(16) u16 Bs[4][256 * 32];   //              64 KB

    const int tid  = threadIdx.x;
    const int lane = tid & 63;
    const int wv   = tid >> 6;           // 0..7
    const int bm = blockIdx.x * 256;
    const int bn = blockIdx.y * 256;

    // staging: lane l -> row wv*16 + (l>>2) (+128 for issue 1), slot l&3
    // holds logical k-slot (l&3)^((l>>3)&3)  (slot ^= (row>>1)&3).
    const int ks = (lane & 3) ^ ((lane >> 3) & 3);
    const int lr = lane >> 2;
    const u16* ag = A  + (size_t)(bm + wv * 16 + lr) * lda + ks * 8;
    const u16* bg = Bt + (size_t)(bn + wv * 16 + lr) * ldb + ks * 8;
    const size_t a128 = (size_t)128 * lda;
    const size_t b128 = (size_t)128 * ldb;
    const int lo = wv * 16 * 32;         // lane-uniform LDS base (u16 units)

    // fragment reads: row wr+m*16+li; logical slot kc stored at kc^((li>>1)&3)
    const int li = lane & 15;
    const int kc = lane >> 4;
    const int wr = (wv >> 2) * 128;      // 0,128
    const int wc = (wv & 3) * 64;        // 0,64,128,192
    const int fo = (kc ^ ((li >> 1) & 3)) * 8;

    f32x4 acc[8][4];
#pragma unroll
    for (int m = 0; m < 8; ++m)
#pragma unroll
        for (int n = 0; n < 4; ++n) acc[m][n] = (f32x4)0.f;

#define STA8(reg, koff)                                                        \
    do {                                                                       \
        __builtin_amdgcn_global_load_lds((as1cv)(ag + (koff)),                 \
            (as3v)&As[reg][lo], 16, 0, 0);                                     \
        __builtin_amdgcn_global_load_lds((as1cv)(ag + a128 + (koff)),          \
            (as3v)&As[reg][lo + 128 * 32], 16, 0, 0);                          \
    } while (0)
#define STB8(reg, koff)                                                        \
    do {                                                                       \
        __builtin_amdgcn_global_load_lds((as1cv)(bg + (koff)),                 \
            (as3v)&Bs[reg][lo], 16, 0, 0);                                     \
        __builtin_amdgcn_global_load_lds((as1cv)(bg + b128 + (koff)),          \
            (as3v)&Bs[reg][lo + 128 * 32], 16, 0, 0);                          \
    } while (0)
#define MFMA16(n0i, n1i)                                                       \
    do {                                                                       \
        __builtin_amdgcn_s_setprio(1);                                         \
        _Pragma("unroll")                                                      \
        for (int m = 0; m < 8; ++m) {                                          \
            acc[m][n0i] = __builtin_amdgcn_mfma_f32_16x16x32_bf16(             \
                af[m], b0, acc[m][n0i], 0, 0, 0);                              \
            acc[m][n1i] = __builtin_amdgcn_mfma_f32_16x16x32_bf16(             \
                af[m], b1, acc[m][n1i], 0, 0, 0);                              \
        }                                                                      \
        __builtin_amdgcn_s_setprio(0);                                         \
    } while (0)
#define BAR()  __builtin_amdgcn_s_barrier()
#define LGKM() do { asm volatile("s_waitcnt lgkmcnt(0)" ::: "memory");         \
                    __builtin_amdgcn_sched_barrier(0); } while (0)

    const int nt = K >> 6;   // K/64 tiles; call sites have nt >= 16
    // prologue: stage tile 0 (kh0 then kh1); wait kh0, leave kh1 in flight
    STA8(0, 0); STB8(0, 0);
    STA8(1, 32); STB8(1, 32);
    asm volatile("s_waitcnt vmcnt(4)" ::: "memory");
    BAR();
    __builtin_amdgcn_sched_barrier(0);

    for (int t = 0; t < nt; ++t) {
        const int d = (t & 1) * 2;        // this tile's region pair
        const int e = d ^ 2;              // next tile's region pair
        const int ko = (t + 1) << 6;
        const bool st = (t + 1 < nt);
        const u16* A0 = &As[d][0];
        const u16* A1 = &As[d + 1][0];
        const u16* B0 = &Bs[d][0];
        const u16* B1 = &Bs[d + 1][0];
        s8v af[8], b0, b1;

        // ---- P1: read A(kh0) m0-7 + B(kh0) n0-1 ; stage A-kh0(t+1)
#pragma unroll
        for (int m = 0; m < 8; ++m)
            af[m] = *(const s8v*)&A0[(wr + m * 16 + li) * 32 + fo];
        b0 = *(const s8v*)&B0[(wc + li) * 32 + fo];
        b1 = *(const s8v*)&B0[(wc + 16 + li) * 32 + fo];
        if (st) STA8(e, ko);
        BAR(); LGKM();
        MFMA16(0, 1);
        BAR();

        // ---- P2: read B(kh0) n2-3 ; stage B-kh0(t+1) ; wait kh1(t)
        b0 = *(const s8v*)&B0[(wc + 32 + li) * 32 + fo];
        b1 = *(const s8v*)&B0[(wc + 48 + li) * 32 + fo];
        if (st) STB8(e, ko);
        BAR(); LGKM();
        MFMA16(2, 3);
        if (st) asm volatile("s_waitcnt vmcnt(4)" ::: "memory");
        else    asm volatile("s_waitcnt vmcnt(0)" ::: "memory");
        BAR();
        __builtin_amdgcn_sched_barrier(0);

        // ---- P3: read A(kh1) m0-7 + B(kh1) n0-1 ; stage A-kh1(t+1)
#pragma unroll
        for (int m = 0; m < 8; ++m)
            af[m] = *(const s8v*)&A1[(wr + m * 16 + li) * 32 + fo];
        b0 = *(const s8v*)&B1[(wc + li) * 32 + fo];
        b1 = *(const s8v*)&B1[(wc + 16 + li) * 32 + fo];
        if (st) STA8(e + 1, ko + 32);
        BAR(); LGKM();
        MFMA16(0, 1);
        BAR();

        // ---- P4: read B(kh1) n2-3 ; stage B-kh1(t+1) ; wait kh0(t+1)
        b0 = *(const s8v*)&B1[(wc + 32 + li) * 32 + fo];
        b1 = *(const s8v*)&B1[(wc + 48 + li) * 32 + fo];
        if (st) STB8(e + 1, ko + 32);
        BAR(); LGKM();
        MFMA16(2, 3);
        if (st) {
            asm volatile("s_waitcnt vmcnt(4)" ::: "memory");
            BAR();
            __builtin_amdgcn_sched_barrier(0);
        }
    }
#undef STA8
#undef STB8
#undef MFMA16
#undef BAR
#undef LGKM

    // C row = bm+wr+m*16+kc*4+j, col = bn+wc+n*16+li
#pragma unroll
    for (int m = 0; m < 8; ++m) {
#pragma unroll
        for (int j = 0; j < 4; ++j) {
            int row = bm + wr + m * 16 + kc * 4 + j;
#pragma unroll
            for (int n = 0; n < 4; ++n) {
                int col = bn + wc + n * 16 + li;
                float v = acc[m][n][j];
                if (MODE == 0) {
                    C0[(size_t)row * ldc0 + col] = v;
                } else {
                    if (bn < DI) C0[(size_t)row * DI + col] = v;
                    else         C1[(size_t)row * DI + col - DI] = v;
                }
            }
        }
    }
}

// ---------------------------------------------------------------- 128^2 2-phase GEMM (out_proj)
// Round-8-proven. fp32 C0 + bf16 Cb outputs.
__global__ __launch_bounds__(256) void gemm_bb2(
    const u16* __restrict__ A, int lda,
    const u16* __restrict__ Bt, int ldb,
    float* __restrict__ C0, u16* __restrict__ Cb, int ldc0, int K)
{
    __shared__ __align__(16) u16 As[2][128 * 32];
    __shared__ __align__(16) u16 Bs[2][128 * 32];

    const int tid  = threadIdx.x;
    const int lane = tid & 63;
    const int wv   = tid >> 6;
    const int bm = blockIdx.x * 128;
    const int bn = blockIdx.y * 128;

    const int ks = (lane & 3) ^ ((lane >> 3) & 3);
    const int sr = wv * 32 + (lane >> 2);
    const u16* ag0 = A  + (size_t)(bm + sr) * lda + ks * 8;
    const u16* ag1 = ag0 + 16 * (size_t)lda;
    const u16* bg0 = Bt + (size_t)(bn + sr) * ldb + ks * 8;
    const u16* bg1 = bg0 + 16 * (size_t)ldb;
    const int lo0 = wv * 1024;
    const int lo1 = wv * 1024 + 512;

    const int li = lane & 15;
    const int kc = lane >> 4;
    const int wr = (wv >> 1) * 64;
    const int wc = (wv & 1) * 64;
    const int fo = (kc ^ ((li >> 1) & 3)) * 8;

    f32x4 acc[4][4];
#pragma unroll
    for (int m = 0; m < 4; ++m)
#pragma unroll
        for (int n = 0; n < 4; ++n) acc[m][n] = (f32x4)0.f;

#define STAGE(buf, kk)                                                         \
    do {                                                                       \
        __builtin_amdgcn_global_load_lds((as1cv)(ag0 + (kk)),                  \
            (as3v)&As[buf][lo0], 16, 0, 0);                                    \
        __builtin_amdgcn_global_load_lds((as1cv)(ag1 + (kk)),                  \
            (as3v)&As[buf][lo1], 16, 0, 0);                                    \
        __builtin_amdgcn_global_load_lds((as1cv)(bg0 + (kk)),                  \
            (as3v)&Bs[buf][lo0], 16, 0, 0);                                    \
        __builtin_amdgcn_global_load_lds((as1cv)(bg1 + (kk)),                  \
            (as3v)&Bs[buf][lo1], 16, 0, 0);                                    \
    } while (0)

    const int nt = K >> 5;
    STAGE(0, 0);
    asm volatile("s_waitcnt vmcnt(0)" ::: "memory");
    __builtin_amdgcn_s_barrier();
    __builtin_amdgcn_sched_barrier(0);

    int cur = 0;
    for (int t = 0; t < nt; ++t) {
        if (t + 1 < nt) STAGE(cur ^ 1, (t + 1) << 5);

        const u16* Ab = &As[cur][0];
        const u16* Bb = &Bs[cur][0];
        s8v af[4], bf[4];
#pragma unroll
        for (int m = 0; m < 4; ++m)
            af[m] = *(const s8v*)&Ab[(wr + m * 16 + li) * 32 + fo];
#pragma unroll
        for (int n = 0; n < 4; ++n)
            bf[n] = *(const s8v*)&Bb[(wc + n * 16 + li) * 32 + fo];
#pragma unroll
        for (int m = 0; m < 4; ++m)
#pragma unroll
            for (int n = 0; n < 4; ++n)
                acc[m][n] = __builtin_amdgcn_mfma_f32_16x16x32_bf16(
                    af[m], bf[n], acc[m][n], 0, 0, 0);

        if (t + 1 < nt) {
            asm volatile("s_waitcnt vmcnt(0)" ::: "memory");
            __builtin_amdgcn_s_barrier();
            __builtin_amdgcn_sched_barrier(0);
            cur ^= 1;
        }
    }
#undef STAGE

#pragma unroll
    for (int m = 0; m < 4; ++m) {
#pragma unroll
        for (int j = 0; j < 4; ++j) {
            int row = bm + wr + m * 16 + kc * 4 + j;
#pragma unroll
            for (int n = 0; n < 4; ++n) {
                int col = bn + wc + n * 16 + li;
                float v = acc[m][n][j];
                C0[(size_t)row * ldc0 + col] = v;
                Cb[(size_t)row * ldc0 + col] = f2bf(v);
            }
        }
    }
}

// ---------------------------------------------------------------- fp32 SGEMM (small ops)
template<int EPI, bool NGUARD, bool SPLITK>
__global__ __launch_bounds__(256) void sgemm_bt(
    const float* __restrict__ A, int lda,
    const float* __restrict__ Bt, int ldb,
    float* __restrict__ C, int ldc,
    const float* __restrict__ bias,
    int M, int N, int K, int kchunk)
{
    __shared__ float As[16][132];
    __shared__ float Bs[16][132];

    const int tid = threadIdx.x;
    const int bm = blockIdx.y * 128;
    const int bn = blockIdx.x * 128;

    int k0 = 0, kend = K;
    if (SPLITK) {
        k0 = blockIdx.z * kchunk;
        kend = k0 + kchunk; if (kend > K) kend = K;
        C += (size_t)blockIdx.z * (size_t)M * (size_t)ldc;
    }

    const int tx = tid & 15;
    const int ty = tid >> 4;
    const int lr = tid >> 2;
    const int lc = (tid & 3) << 2;

    float acc[8][8];
#pragma unroll
    for (int i = 0; i < 8; ++i)
#pragma unroll
        for (int j = 0; j < 8; ++j) acc[i][j] = 0.f;

    for (int kk = k0; kk < kend; kk += 16) {
#pragma unroll
        for (int p = 0; p < 2; ++p) {
            int r = lr + p * 64;
            float4 v = *(const float4*)(A + (size_t)(bm + r) * lda + kk + lc);
            As[lc + 0][r] = v.x; As[lc + 1][r] = v.y;
            As[lc + 2][r] = v.z; As[lc + 3][r] = v.w;
        }
#pragma unroll
        for (int p = 0; p < 2; ++p) {
            int r = lr + p * 64;
            float4 v = make_float4(0.f, 0.f, 0.f, 0.f);
            if (!NGUARD || (bn + r) < N)
                v = *(const float4*)(Bt + (size_t)(bn + r) * ldb + kk + lc);
            Bs[lc + 0][r] = v.x; Bs[lc + 1][r] = v.y;
            Bs[lc + 2][r] = v.z; Bs[lc + 3][r] = v.w;
        }
        __syncthreads();
#pragma unroll
        for (int k = 0; k < 16; ++k) {
            float4 a0 = *(const float4*)&As[k][ty * 4];
            float4 a1 = *(const float4*)&As[k][64 + ty * 4];
            float4 b0 = *(const float4*)&Bs[k][tx * 4];
            float4 b1 = *(const float4*)&Bs[k][64 + tx * 4];
            float av[8] = {a0.x, a0.y, a0.z, a0.w, a1.x, a1.y, a1.z, a1.w};
            float bv[8] = {b0.x, b0.y, b0.z, b0.w, b1.x, b1.y, b1.z, b1.w};
#pragma unroll
            for (int i = 0; i < 8; ++i)
#pragma unroll
                for (int j = 0; j < 8; ++j)
                    acc[i][j] += av[i] * bv[j];
        }
        __syncthreads();
    }

#pragma unroll
    for (int p = 0; p < 2; ++p) {
#pragma unroll
        for (int ii = 0; ii < 4; ++ii) {
            int row = bm + p * 64 + ty * 4 + ii;
#pragma unroll
            for (int q = 0; q < 2; ++q) {
                int col = bn + q * 64 + tx * 4;
                if (NGUARD && col >= N) continue;
                float4 v;
                float* vp = &v.x;
#pragma unroll
                for (int jj = 0; jj < 4; ++jj) {
                    float x = acc[p * 4 + ii][q * 4 + jj];
                    if (EPI == 1) {
                        x += bias[col + jj];
                        x = (x > 20.f) ? x : log1pf(__expf(x));
                    }
                    vp[jj] = x;
                }
                *(float4*)(C + (size_t)row * ldc + col) = v;
            }
        }
    }
}

// ---------------------------------------------------------------- split-K reduce
__global__ __launch_bounds__(256) void reduce8_kernel(
    const float* __restrict__ part, float* __restrict__ out, int n)
{
    int i = blockIdx.x * 256 + threadIdx.x;
    if (i < n) {
        float s = 0.f;
#pragma unroll
        for (int j = 0; j < 8; ++j) s += part[(size_t)j * n + i];
        out[i] = s;
    }
}

// ---------------------------------------------------------------- conv + SiLU
__global__ __launch_bounds__(256) void conv_silu_kernel(
    const float* __restrict__ XZu, const float* __restrict__ cw,
    const float* __restrict__ cb, float* __restrict__ U)
{
    int idx = blockIdx.x * 256 + threadIdx.x;
    int c4 = idx & 511;
    int row = idx >> 9;
    int t = row & (L_SEQ - 1);
    int c = c4 << 2;

    float4 acc;
    acc.x = cb[c]; acc.y = cb[c + 1]; acc.z = cb[c + 2]; acc.w = cb[c + 3];
    float4 w0 = *(const float4*)(cw + (size_t)(c + 0) * 4);
    float4 w1 = *(const float4*)(cw + (size_t)(c + 1) * 4);
    float4 w2 = *(const float4*)(cw + (size_t)(c + 2) * 4);
    float4 w3 = *(const float4*)(cw + (size_t)(c + 3) * 4);
#pragma unroll
    for (int k = 0; k < 4; ++k) {
        int tt = t - 3 + k;
        if (tt >= 0) {
            float4 xv = *(const float4*)(XZu + (size_t)(row - 3 + k) * DI + c);
            acc.x += xv.x * ((&w0.x)[k]);
            acc.y += xv.y * ((&w1.x)[k]);
            acc.z += xv.z * ((&w2.x)[k]);
            acc.w += xv.w * ((&w3.x)[k]);
        }
    }
    acc.x = acc.x / (1.f + __expf(-acc.x));
    acc.y = acc.y / (1.f + __expf(-acc.y));
    acc.z = acc.z / (1.f + __expf(-acc.z));
    acc.w = acc.w / (1.f + __expf(-acc.w));
    *(float4*)(U + (size_t)row * DI + c) = acc;
}

// ---------------------------------------------------------------- fused chunked scan
__global__ __launch_bounds__(256) void scan_fused(
    const float* __restrict__ U, const float* __restrict__ DELTA,
    const float* __restrict__ DBL, const float* __restrict__ ZF,
    const float* __restrict__ A_log, const float* __restrict__ Dskip,
    u16* __restrict__ Yb)
{
    __shared__ float ps[EL][NCH][DS][2];   // 32 KB (P,S)
    __shared__ float hs[EL][NCH][DS];      // 16 KB (h_start)

    const int tid   = threadIdx.x;
    const int el    = tid & (EL - 1);
    const int chunk = tid >> 3;            // 0..31
    const int bid   = blockIdx.x;
    const int b     = bid >> 8;            // DI/EL = 256 e-groups
    const int e     = (bid & 255) * EL + el;
    const int t0    = chunk * CHL;

    float Ae[DS];
#pragma unroll
    for (int s = 0; s < DS; ++s)
        Ae[s] = -__expf(A_log[(size_t)e * DS + s]);

    const float* up = U     + (size_t)b * L_SEQ * DI + e;
    const float* dp = DELTA + (size_t)b * L_SEQ * DI + e;
    const float* zp = ZF    + (size_t)b * L_SEQ * DI + e;
    const float* bp = DBL   + ((size_t)b * L_SEQ + t0) * DBLC + DTR;
    const float* cp = bp + DS;
    u16* yp = Yb + (size_t)b * L_SEQ * DI + e;

    // ---- phase A: per-chunk transfer function (P, S) per state
    float P[DS], S[DS];
#pragma unroll
    for (int s = 0; s < DS; ++s) { P[s] = 1.f; S[s] = 0.f; }

    {
        float u0 = up[(size_t)t0 * DI];
        float d0 = dp[(size_t)t0 * DI];
        float4 B0[4];
#pragma unroll
        for (int q = 0; q < 4; ++q) B0[q] = *(const float4*)(bp + q * 4);

        for (int i = 0; i < CHL; ++i) {
            float u1 = 0.f, d1 = 0.f;
            float4 B1[4] = {};
            if (i + 1 < CHL) {
                u1 = up[(size_t)(t0 + i + 1) * DI];
                d1 = dp[(size_t)(t0 + i + 1) * DI];
#pragma unroll
                for (int q = 0; q < 4; ++q)
                    B1[q] = *(const float4*)(bp + (i + 1) * DBLC + q * 4);
            }
            float du = d0 * u0;
            const float* Bf = (const float*)&B0[0];
#pragma unroll
            for (int s = 0; s < DS; ++s) {
                float a = __expf(d0 * Ae[s]);
                P[s] *= a;
                S[s] = S[s] * a + du * Bf[s];
            }
            u0 = u1; d0 = d1;
#pragma unroll
            for (int q = 0; q < 4; ++q) B0[q] = B1[q];
        }
    }
#pragma unroll
    for (int s = 0; s < DS; ++s) {
        ps[el][chunk][s][0] = P[s];
        ps[el][chunk][s][1] = S[s];
    }
    __syncthreads();

    // ---- phase B: in-LDS chunk prefix (same order as serial combine)
    if (tid < EL * DS) {
        int pel = tid >> 4;
        int s   = tid & 15;
        float h = 0.f;
#pragma unroll
        for (int c = 0; c < NCH; ++c) {
            hs[pel][c][s] = h;
            h = ps[pel][c][s][0] * h + ps[pel][c][s][1];
        }
    }
    __syncthreads();

    // ---- phase C: rescan from h_start, emit gated bf16 y
    float Dk = Dskip[e];
    float h[DS];
#pragma unroll
    for (int s = 0; s < DS; ++s) h[s] = hs[el][chunk][s];

    {
        float u0 = up[(size_t)t0 * DI];
        float d0 = dp[(size_t)t0 * DI];
        float z0 = zp[(size_t)t0 * DI];
        float4 B0[4], C0[4];
#pragma unroll
        for (int q = 0; q < 4; ++q) {
            B0[q] = *(const float4*)(bp + q * 4);
            C0[q] = *(const float4*)(cp + q * 4);
        }

        for (int i = 0; i < CHL; ++i) {
            float u1 = 0.f, d1 = 0.f, z1 = 0.f;
            float4 B1[4] = {}, C1[4] = {};
            if (i + 1 < CHL) {
                u1 = up[(size_t)(t0 + i + 1) * DI];
                d1 = dp[(size_t)(t0 + i + 1) * DI];
                z1 = zp[(size_t)(t0 + i + 1) * DI];
#pragma unroll
                for (int q = 0; q < 4; ++q) {
                    B1[q] = *(const float4*)(bp + (i + 1) * DBLC + q * 4);
                    C1[q] = *(const float4*)(cp + (i + 1) * DBLC + q * 4);
                }
            }
            float du = d0 * u0;
            const float* Bf = (const float*)&B0[0];
            const float* Cf = (const float*)&C0[0];
            float y0 = 0.f, y1 = 0.f, y2 = 0.f, y3 = 0.f;
#pragma unroll
            for (int s = 0; s < DS; ++s) {
                float a = __expf(d0 * Ae[s]);
                h[s] = h[s] * a + du * Bf[s];
                float hc = h[s] * Cf[s];
                if ((s & 3) == 0) y0 += hc;
                else if ((s & 3) == 1) y1 += hc;
                else if ((s & 3) == 2) y2 += hc;
                else y3 += hc;
            }
            float p = (y0 + y1) + (y2 + y3);
            float g = z0 / (1.f + __expf(-z0));
            yp[(size_t)(t0 + i) * DI] = f2bf((p + u0 * Dk) * g);
            u0 = u1; d0 = d1; z0 = z1;
#pragma unroll
            for (int q = 0; q < 4; ++q) { B0[q] = B1[q]; C0[q] = C1[q]; }
        }
    }
}

// ---------------------------------------------------------------- layernorm (bf16 out)
__global__ __launch_bounds__(256) void layernorm_kernel(
    const float* __restrict__ X, const float* __restrict__ g,
    const float* __restrict__ be, u16* __restrict__ XNb)
{
    __shared__ float red[4];
    int row = blockIdx.x;
    int tid = threadIdx.x;
    float4 v = ((const float4*)(X + (size_t)row * DM))[tid];

    float ssum = v.x + v.y + v.z + v.w;
#pragma unroll
    for (int o = 32; o >= 1; o >>= 1) ssum += __shfl_xor(ssum, o);
    if ((tid & 63) == 0) red[tid >> 6] = ssum;
    __syncthreads();
    float mean = (red[0] + red[1] + red[2] + red[3]) * (1.f / DM);
    __syncthreads();

    float dx = v.x - mean, dy = v.y - mean, dz = v.z - mean, dw = v.w - mean;
    float sq = dx * dx + dy * dy + dz * dz + dw * dw;
#pragma unroll
    for (int o = 32; o >= 1; o >>= 1) sq += __shfl_xor(sq, o);
    if ((tid & 63) == 0) red[tid >> 6] = sq;
    __syncthreads();
    float var = (red[0] + red[1] + red[2] + red[3]) * (1.f / DM);
    float rs = rsqrtf(var + 1e-5f);

    float4 gv = ((const float4*)g)[tid];
    float4 bv = ((const float4*)be)[tid];
    ushort4 o;
    o.x = f2bf(dx * rs * gv.x + bv.x);
    o.y = f2bf(dy * rs * gv.y + bv.y);
    o.z = f2bf(dz * rs * gv.z + bv.z);
    o.w = f2bf(dw * rs * gv.w + bv.w);
    ((ushort4*)(XNb + (size_t)row * DM))[tid] = o;
}

// ---------------------------------------------------------------- launch
extern "C" void kernel_launch(void* const* d_in, const int* in_sizes, int n_in,
                              void* d_out, int out_size, void* d_ws, size_t ws_size,
                              hipStream_t stream)
{
    const int*   tokens = (const int*)d_in[0];
    const float* emb    = (const float*)d_in[1];
    const float* in_w   = (const float*)d_in[2];
    const float* conv_w = (const float*)d_in[3];
    const float* conv_b = (const float*)d_in[4];
    const float* xp_w   = (const float*)d_in[5];
    const float* dt_w   = (const float*)d_in[6];
    const float* dt_b   = (const float*)d_in[7];
    const float* A_log  = (const float*)d_in[8];
    const float* Dskip  = (const float*)d_in[9];
    const float* out_w  = (const float*)d_in[10];
    const float* gamma  = (const float*)d_in[11];
    const float* beta   = (const float*)d_in[12];
    const float* lm_w   = (const float*)d_in[13];
    float* out = (float*)d_out;

    // ---- workspace: 43.39M floats = 173.6 MB (round-4..13-proven size).
    float* ws = (float*)d_ws;
    size_t off = 0;
    float* X     = ws + off; off += (size_t)BL * DM;        //  4.19M  fp32 LN input
    float* XZu   = ws + off; off += (size_t)BL * DI;        //  8.39M
    float* U     = ws + off; off += (size_t)BL * DI;        //  8.39M
    float* ZF    = ws + off; off += (size_t)BL * DI;        //  8.39M
    float* DELTA = ws + off; off += (size_t)BL * DI;        //  8.39M
    float* DBL   = ws + off; off += (size_t)BL * DBLC;      //  0.39M
    u16* Xb     = (u16*)(ws + off); off += (size_t)BL * DM / 2;      // 2.10M
    u16* wb_in  = (u16*)(ws + off); off += (size_t)2 * DI * DM / 2;  // 2.10M
    u16* wb_out = (u16*)(ws + off); off += (size_t)DM * DI / 2;      // 1.05M
    // aliases (lifetime-checked):
    u16* Yb    = (u16*)XZu;   // scan out; XZu dead after conv_silu
    u16* wb_lm = (u16*)XZu;   // over [XZu|U]; dead after layer-2 out_proj
    float* PART = DELTA;      // split-K partials; consumed before dt_proj
    u16* XNb   = Xb;          // LN out; Xb dead after layer-2 in_proj

    embed_kernel<<<BL, 256, 0, stream>>>(tokens, emb, Xb);

    const int SCAN_GRID = BATCH * (DI / EL);  // 512 blocks

    for (int l = 0; l < 2; ++l) {
        const float* cwp = conv_w + (size_t)l * DI * 4;
        const float* cbp = conv_b + (size_t)l * DI;
        const float* xw  = xp_w   + (size_t)l * DBLC * DI;
        const float* dw  = dt_w   + (size_t)l * DI * DTR;
        const float* dbp = dt_b   + (size_t)l * DI;
        const float* alp = A_log  + (size_t)l * DI * DS;
        const float* dkp = Dskip  + (size_t)l * DI;

        // both weight converts in one dispatch
        const int n8i = 2 * DI * DM / 8, n8o = DM * DI / 8;
        cvt2_bf16_kernel<<<(n8i + n8o + 255) / 256, 256, 0, stream>>>(
            in_w + (size_t)l * 2 * DI * DM, wb_in, n8i,
            out_w + (size_t)l * DM * DI, wb_out, n8o);

        // xz = x @ in_w^T : [4096,4096] K=1024; u-half -> XZu, z-half -> ZF
        gemm_8p<1><<<dim3(16, 16), 512, 0, stream>>>(
            Xb, DM, wb_in, DM, XZu, ZF, 0, DM);
        // u = silu(conv(XZu))
        conv_silu_kernel<<<(BL * DI / 4) / 256, 256, 0, stream>>>(XZu, cwp, cbp, U);
        // x_dbl = u @ xp_w^T : [4096,96] fp32 split-K
        sgemm_bt<0, true, true><<<dim3(1, 32, 8), 256, 0, stream>>>(
            U, DI, xw, DI, PART, DBLC, nullptr, BL, DBLC, DI, DI / 8);
        reduce8_kernel<<<(BL * DBLC + 255) / 256, 256, 0, stream>>>(
            PART, DBL, BL * DBLC);
        // delta = softplus(dt @ dt_w^T + dt_b) fp32 (K=64)
        sgemm_bt<1, false, false><<<dim3(16, 32), 256, 0, stream>>>(
            DBL, DBLC, dw, DTR, DELTA, DI, dbp, BL, DI, DTR, 0);
        // fused chunked scan -> bf16 Yb (aliases XZu)
        scan_fused<<<SCAN_GRID, 256, 0, stream>>>(
            U, DELTA, DBL, ZF, alp, dkp, Yb);
        // x = y @ out_w^T : [4096,1024] K=2048 (proven 128^2 2-phase)
        gemm_bb2<<<dim3(32, 8), 256, 0, stream>>>(
            Yb, DI, wb_out, DI, X, Xb, DM, DI);
    }

    cvt_bf16_kernel<<<((size_t)VOCAB * DM / 8 + 255) / 256, 256, 0, stream>>>(
        lm_w, wb_lm, VOCAB * DM / 8);

    layernorm_kernel<<<BL, 256, 0, stream>>>(X, gamma, beta, XNb);

    // logits = xn @ lm_head^T : [4096,32000] K=1024 (8-phase-style)
    gemm_8p<0><<<dim3(16, 125), 512, 0, stream>>>(
        XNb, DM, wb_lm, DM, out, nullptr, VOCAB, DM);
}

// Round 15
// 992.760 us; speedup vs baseline: 1.1147x; 1.0117x over previous
//
#include <hip/hip_runtime.h>
#include <hip/hip_bf16.h>

#define L_SEQ 2048
#define BATCH 2
#define DM    1024          // d_model
#define DI    2048          // d_inner
#define DS    16            // d_state
#define DTR   64            // dt_rank
#define DBLC  96            // dt_rank + 2*d_state
#define VOCAB 32000
#define BL    (BATCH * L_SEQ)   // 4096 tokens
#define NCH   32            // scan chunks
#define CHL   (L_SEQ / NCH) // 64 steps per chunk
#define EL    8             // channels per scan block

typedef unsigned short u16;
typedef short s8v  __attribute__((ext_vector_type(8)));   // 8 bf16
typedef float f32x4 __attribute__((ext_vector_type(4)));

typedef __attribute__((address_space(1))) const void* as1cv;
typedef __attribute__((address_space(3))) void*       as3v;

// round-to-nearest-even fp32 -> bf16
static __device__ __forceinline__ u16 f2bf(float f) {
    unsigned u = __builtin_bit_cast(unsigned, f);
    u += 0x7fffu + ((u >> 16) & 1u);
    return (u16)(u >> 16);
}

// ---------------------------------------------------------------- fp32 -> bf16 converts
__global__ __launch_bounds__(256) void cvt_bf16_kernel(
    const float* __restrict__ in, u16* __restrict__ out, int n8)
{
    int i = blockIdx.x * 256 + threadIdx.x;
    if (i >= n8) return;
    const float4* p = (const float4*)in + 2 * (size_t)i;
    float4 a = p[0], b = p[1];
    s8v o;
    o[0] = (short)f2bf(a.x); o[1] = (short)f2bf(a.y);
    o[2] = (short)f2bf(a.z); o[3] = (short)f2bf(a.w);
    o[4] = (short)f2bf(b.x); o[5] = (short)f2bf(b.y);
    o[6] = (short)f2bf(b.z); o[7] = (short)f2bf(b.w);
    ((s8v*)out)[i] = o;
}

// two tensors in one dispatch (per-layer in_w + out_w)
__global__ __launch_bounds__(256) void cvt2_bf16_kernel(
    const float* __restrict__ inA, u16* __restrict__ outA, int n8A,
    const float* __restrict__ inB, u16* __restrict__ outB, int n8B)
{
    int i = blockIdx.x * 256 + threadIdx.x;
    const float* src; u16* dst; int idx;
    if (i < n8A) { src = inA; dst = outA; idx = i; }
    else if (i < n8A + n8B) { src = inB; dst = outB; idx = i - n8A; }
    else return;
    const float4* p = (const float4*)src + 2 * (size_t)idx;
    float4 a = p[0], b = p[1];
    s8v o;
    o[0] = (short)f2bf(a.x); o[1] = (short)f2bf(a.y);
    o[2] = (short)f2bf(a.z); o[3] = (short)f2bf(a.w);
    o[4] = (short)f2bf(b.x); o[5] = (short)f2bf(b.y);
    o[6] = (short)f2bf(b.z); o[7] = (short)f2bf(b.w);
    ((s8v*)dst)[idx] = o;
}

// ---------------------------------------------------------------- embedding (bf16 out)
__global__ __launch_bounds__(256) void embed_kernel(
    const int* __restrict__ tok, const float* __restrict__ emb,
    u16* __restrict__ Xb)
{
    int row = blockIdx.x;
    int t = tok[row];
    float4 v = ((const float4*)(emb + (size_t)t * DM))[threadIdx.x];
    ushort4 o;
    o.x = f2bf(v.x); o.y = f2bf(v.y); o.z = f2bf(v.z); o.w = f2bf(v.w);
    ((ushort4*)(Xb + (size_t)row * DM))[threadIdx.x] = o;
}

// ---------------------------------------------------------------- 8-phase-style GEMM
// C = A[M,K](bf16) * Bt[N,K](bf16)^T.  256x256 tile, BK=64 (2 K-halves),
// 512 thr = 8 waves (2M x 4N), per-wave 128x64 = 8m x 4n frags.
// Per-phase interleave (r14-proven: lm 350->322, MfmaUtil 36%): 4 phases
// per K-tile, each = {ds_read one fragment subtile || stage ONE half-tile
// of t+1 || barrier || lgkmcnt(0) || setprio(1) 16 MFMA setprio(0) ||
// [vmcnt] barrier}.  LDS [dbuf][khalf] = 128 KB.
// r15: MODE 0 (lm_head) uses NON-TEMPORAL C stores — the 512 MB logit
// stream is write-once and was evicting B panels from L2/L3 (FETCH 289 MB
// vs 74 MB ideal).
// HAZARD PROOF: see round-14 notes (W1 stage-over-read: target region's
// last readers lgkmcnt-completed before a barrier preceding the stage;
// W2 read-before-land: vmcnt(4) + barrier covers the 4 loads staged one
// full tile earlier).  Accumulation k-order bit-identical to 2-phase.
// MODE 0: fp32 C0 (ldc0, NT stores).  MODE 1: in_proj split u/z.
template<int MODE>
__global__ __launch_bounds__(512) void gemm_8p(
    const u16* __restrict__ A, int lda,
    const u16* __restrict__ Bt, int ldb,
    float* __restrict__ C0, float* __restrict__ C1,
    int ldc0, int K)
{
    __shared__ __align__(16) u16 As[4][256 * 32];   // [dbuf*2+kh]  64 KB
    __shared__ __align__(16) u16 Bs[4][256 * 32];   //              64 KB

    const int tid  = threadIdx.x;
    const int lane = tid & 63;
    const int wv   = tid >> 6;           // 0..7
    const int bm = blockIdx.x * 256;
    const int bn = blockIdx.y * 256;

    const int ks = (lane & 3) ^ ((lane >> 3) & 3);
    const int lr = lane >> 2;
    const u16* ag = A  + (size_t)(bm + wv * 16 + lr) * lda + ks * 8;
    const u16* bg = Bt + (size_t)(bn + wv * 16 + lr) * ldb + ks * 8;
    const size_t a128 = (size_t)128 * lda;
    const size_t b128 = (size_t)128 * ldb;
    const int lo = wv * 16 * 32;         // lane-uniform LDS base (u16 units)

    const int li = lane & 15;
    const int kc = lane >> 4;
    const int wr = (wv >> 2) * 128;      // 0,128
    const int wc = (wv & 3) * 64;        // 0,64,128,192
    const int fo = (kc ^ ((li >> 1) & 3)) * 8;

    f32x4 acc[8][4];
#pragma unroll
    for (int m = 0; m < 8; ++m)
#pragma unroll
        for (int n = 0; n < 4; ++n) acc[m][n] = (f32x4)0.f;

#define STA8(reg, koff)                                                        \
    do {                                                                       \
        __builtin_amdgcn_global_load_lds((as1cv)(ag + (koff)),                 \
            (as3v)&As[reg][lo], 16, 0, 0);                                     \
        __builtin_amdgcn_global_load_lds((as1cv)(ag + a128 + (koff)),          \
            (as3v)&As[reg][lo + 128 * 32], 16, 0, 0);                          \
    } while (0)
#define STB8(reg, koff)                                                        \
    do {                                                                       \
        __builtin_amdgcn_global_load_lds((as1cv)(bg + (koff)),                 \
            (as3v)&Bs[reg][lo], 16, 0, 0);                                     \
        __builtin_amdgcn_global_load_lds((as1cv)(bg + b128 + (koff)),          \
            (as3v)&Bs[reg][lo + 128 * 32], 16, 0, 0);                          \
    } while (0)
#define MFMA16(n0i, n1i)                                                       \
    do {                                                                       \
        __builtin_amdgcn_s_setprio(1);                                         \
        _Pragma("unroll")                                                      \
        for (int m = 0; m < 8; ++m) {                                          \
            acc[m][n0i] = __builtin_amdgcn_mfma_f32_16x16x32_bf16(             \
                af[m], b0, acc[m][n0i], 0, 0, 0);                              \
            acc[m][n1i] = __builtin_amdgcn_mfma_f32_16x16x32_bf16(             \
                af[m], b1, acc[m][n1i], 0, 0, 0);                              \
        }                                                                      \
        __builtin_amdgcn_s_setprio(0);                                         \
    } while (0)
#define BAR()  __builtin_amdgcn_s_barrier()
#define LGKM() do { asm volatile("s_waitcnt lgkmcnt(0)" ::: "memory");         \
                    __builtin_amdgcn_sched_barrier(0); } while (0)

    const int nt = K >> 6;   // K/64 tiles; call sites have nt >= 16
    STA8(0, 0); STB8(0, 0);
    STA8(1, 32); STB8(1, 32);
    asm volatile("s_waitcnt vmcnt(4)" ::: "memory");
    BAR();
    __builtin_amdgcn_sched_barrier(0);

    for (int t = 0; t < nt; ++t) {
        const int d = (t & 1) * 2;
        const int e = d ^ 2;
        const int ko = (t + 1) << 6;
        const bool st = (t + 1 < nt);
        const u16* A0 = &As[d][0];
        const u16* A1 = &As[d + 1][0];
        const u16* B0 = &Bs[d][0];
        const u16* B1 = &Bs[d + 1][0];
        s8v af[8], b0, b1;

        // ---- P1: read A(kh0) m0-7 + B(kh0) n0-1 ; stage A-kh0(t+1)
#pragma unroll
        for (int m = 0; m < 8; ++m)
            af[m] = *(const s8v*)&A0[(wr + m * 16 + li) * 32 + fo];
        b0 = *(const s8v*)&B0[(wc + li) * 32 + fo];
        b1 = *(const s8v*)&B0[(wc + 16 + li) * 32 + fo];
        if (st) STA8(e, ko);
        BAR(); LGKM();
        MFMA16(0, 1);
        BAR();

        // ---- P2: read B(kh0) n2-3 ; stage B-kh0(t+1) ; wait kh1(t)
        b0 = *(const s8v*)&B0[(wc + 32 + li) * 32 + fo];
        b1 = *(const s8v*)&B0[(wc + 48 + li) * 32 + fo];
        if (st) STB8(e, ko);
        BAR(); LGKM();
        MFMA16(2, 3);
        if (st) asm volatile("s_waitcnt vmcnt(4)" ::: "memory");
        else    asm volatile("s_waitcnt vmcnt(0)" ::: "memory");
        BAR();
        __builtin_amdgcn_sched_barrier(0);

        // ---- P3: read A(kh1) m0-7 + B(kh1) n0-1 ; stage A-kh1(t+1)
#pragma unroll
        for (int m = 0; m < 8; ++m)
            af[m] = *(const s8v*)&A1[(wr + m * 16 + li) * 32 + fo];
        b0 = *(const s8v*)&B1[(wc + li) * 32 + fo];
        b1 = *(const s8v*)&B1[(wc + 16 + li) * 32 + fo];
        if (st) STA8(e + 1, ko + 32);
        BAR(); LGKM();
        MFMA16(0, 1);
        BAR();

        // ---- P4: read B(kh1) n2-3 ; stage B-kh1(t+1) ; wait kh0(t+1)
        b0 = *(const s8v*)&B1[(wc + 32 + li) * 32 + fo];
        b1 = *(const s8v*)&B1[(wc + 48 + li) * 32 + fo];
        if (st) STB8(e + 1, ko + 32);
        BAR(); LGKM();
        MFMA16(2, 3);
        if (st) {
            asm volatile("s_waitcnt vmcnt(4)" ::: "memory");
            BAR();
            __builtin_amdgcn_sched_barrier(0);
        }
    }
#undef STA8
#undef STB8
#undef MFMA16
#undef BAR
#undef LGKM

    // C row = bm+wr+m*16+kc*4+j, col = bn+wc+n*16+li
#pragma unroll
    for (int m = 0; m < 8; ++m) {
#pragma unroll
        for (int j = 0; j < 4; ++j) {
            int row = bm + wr + m * 16 + kc * 4 + j;
#pragma unroll
            for (int n = 0; n < 4; ++n) {
                int col = bn + wc + n * 16 + li;
                float v = acc[m][n][j];
                if (MODE == 0) {
                    // logits: write-once stream — non-temporal to avoid
                    // evicting B panels from L2/L3
                    __builtin_nontemporal_store(v, &C0[(size_t)row * ldc0 + col]);
                } else {
                    if (bn < DI) C0[(size_t)row * DI + col] = v;
                    else         C1[(size_t)row * DI + col - DI] = v;
                }
            }
        }
    }
}

// ---------------------------------------------------------------- 128^2 2-phase GEMM (out_proj)
// Round-8-proven. fp32 C0 + bf16 Cb outputs.
__global__ __launch_bounds__(256) void gemm_bb2(
    const u16* __restrict__ A, int lda,
    const u16* __restrict__ Bt, int ldb,
    float* __restrict__ C0, u16* __restrict__ Cb, int ldc0, int K)
{
    __shared__ __align__(16) u16 As[2][128 * 32];
    __shared__ __align__(16) u16 Bs[2][128 * 32];

    const int tid  = threadIdx.x;
    const int lane = tid & 63;
    const int wv   = tid >> 6;
    const int bm = blockIdx.x * 128;
    const int bn = blockIdx.y * 128;

    const int ks = (lane & 3) ^ ((lane >> 3) & 3);
    const int sr = wv * 32 + (lane >> 2);
    const u16* ag0 = A  + (size_t)(bm + sr) * lda + ks * 8;
    const u16* ag1 = ag0 + 16 * (size_t)lda;
    const u16* bg0 = Bt + (size_t)(bn + sr) * ldb + ks * 8;
    const u16* bg1 = bg0 + 16 * (size_t)ldb;
    const int lo0 = wv * 1024;
    const int lo1 = wv * 1024 + 512;

    const int li = lane & 15;
    const int kc = lane >> 4;
    const int wr = (wv >> 1) * 64;
    const int wc = (wv & 1) * 64;
    const int fo = (kc ^ ((li >> 1) & 3)) * 8;

    f32x4 acc[4][4];
#pragma unroll
    for (int m = 0; m < 4; ++m)
#pragma unroll
        for (int n = 0; n < 4; ++n) acc[m][n] = (f32x4)0.f;

#define STAGE(buf, kk)                                                         \
    do {                                                                       \
        __builtin_amdgcn_global_load_lds((as1cv)(ag0 + (kk)),                  \
            (as3v)&As[buf][lo0], 16, 0, 0);                                    \
        __builtin_amdgcn_global_load_lds((as1cv)(ag1 + (kk)),                  \
            (as3v)&As[buf][lo1], 16, 0, 0);                                    \
        __builtin_amdgcn_global_load_lds((as1cv)(bg0 + (kk)),                  \
            (as3v)&Bs[buf][lo0], 16, 0, 0);                                    \
        __builtin_amdgcn_global_load_lds((as1cv)(bg1 + (kk)),                  \
            (as3v)&Bs[buf][lo1], 16, 0, 0);                                    \
    } while (0)

    const int nt = K >> 5;
    STAGE(0, 0);
    asm volatile("s_waitcnt vmcnt(0)" ::: "memory");
    __builtin_amdgcn_s_barrier();
    __builtin_amdgcn_sched_barrier(0);

    int cur = 0;
    for (int t = 0; t < nt; ++t) {
        if (t + 1 < nt) STAGE(cur ^ 1, (t + 1) << 5);

        const u16* Ab = &As[cur][0];
        const u16* Bb = &Bs[cur][0];
        s8v af[4], bf[4];
#pragma unroll
        for (int m = 0; m < 4; ++m)
            af[m] = *(const s8v*)&Ab[(wr + m * 16 + li) * 32 + fo];
#pragma unroll
        for (int n = 0; n < 4; ++n)
            bf[n] = *(const s8v*)&Bb[(wc + n * 16 + li) * 32 + fo];
#pragma unroll
        for (int m = 0; m < 4; ++m)
#pragma unroll
            for (int n = 0; n < 4; ++n)
                acc[m][n] = __builtin_amdgcn_mfma_f32_16x16x32_bf16(
                    af[m], bf[n], acc[m][n], 0, 0, 0);

        if (t + 1 < nt) {
            asm volatile("s_waitcnt vmcnt(0)" ::: "memory");
            __builtin_amdgcn_s_barrier();
            __builtin_amdgcn_sched_barrier(0);
            cur ^= 1;
        }
    }
#undef STAGE

#pragma unroll
    for (int m = 0; m < 4; ++m) {
#pragma unroll
        for (int j = 0; j < 4; ++j) {
            int row = bm + wr + m * 16 + kc * 4 + j;
#pragma unroll
            for (int n = 0; n < 4; ++n) {
                int col = bn + wc + n * 16 + li;
                float v = acc[m][n][j];
                C0[(size_t)row * ldc0 + col] = v;
                Cb[(size_t)row * ldc0 + col] = f2bf(v);
            }
        }
    }
}

// ---------------------------------------------------------------- fp32 SGEMM (small ops)
template<int EPI, bool NGUARD, bool SPLITK>
__global__ __launch_bounds__(256) void sgemm_bt(
    const float* __restrict__ A, int lda,
    const float* __restrict__ Bt, int ldb,
    float* __restrict__ C, int ldc,
    const float* __restrict__ bias,
    int M, int N, int K, int kchunk)
{
    __shared__ float As[16][132];
    __shared__ float Bs[16][132];

    const int tid = threadIdx.x;
    const int bm = blockIdx.y * 128;
    const int bn = blockIdx.x * 128;

    int k0 = 0, kend = K;
    if (SPLITK) {
        k0 = blockIdx.z * kchunk;
        kend = k0 + kchunk; if (kend > K) kend = K;
        C += (size_t)blockIdx.z * (size_t)M * (size_t)ldc;
    }

    const int tx = tid & 15;
    const int ty = tid >> 4;
    const int lr = tid >> 2;
    const int lc = (tid & 3) << 2;

    float acc[8][8];
#pragma unroll
    for (int i = 0; i < 8; ++i)
#pragma unroll
        for (int j = 0; j < 8; ++j) acc[i][j] = 0.f;

    for (int kk = k0; kk < kend; kk += 16) {
#pragma unroll
        for (int p = 0; p < 2; ++p) {
            int r = lr + p * 64;
            float4 v = *(const float4*)(A + (size_t)(bm + r) * lda + kk + lc);
            As[lc + 0][r] = v.x; As[lc + 1][r] = v.y;
            As[lc + 2][r] = v.z; As[lc + 3][r] = v.w;
        }
#pragma unroll
        for (int p = 0; p < 2; ++p) {
            int r = lr + p * 64;
            float4 v = make_float4(0.f, 0.f, 0.f, 0.f);
            if (!NGUARD || (bn + r) < N)
                v = *(const float4*)(Bt + (size_t)(bn + r) * ldb + kk + lc);
            Bs[lc + 0][r] = v.x; Bs[lc + 1][r] = v.y;
            Bs[lc + 2][r] = v.z; Bs[lc + 3][r] = v.w;
        }
        __syncthreads();
#pragma unroll
        for (int k = 0; k < 16; ++k) {
            float4 a0 = *(const float4*)&As[k][ty * 4];
            float4 a1 = *(const float4*)&As[k][64 + ty * 4];
            float4 b0 = *(const float4*)&Bs[k][tx * 4];
            float4 b1 = *(const float4*)&Bs[k][64 + tx * 4];
            float av[8] = {a0.x, a0.y, a0.z, a0.w, a1.x, a1.y, a1.z, a1.w};
            float bv[8] = {b0.x, b0.y, b0.z, b0.w, b1.x, b1.y, b1.z, b1.w};
#pragma unroll
            for (int i = 0; i < 8; ++i)
#pragma unroll
                for (int j = 0; j < 8; ++j)
                    acc[i][j] += av[i] * bv[j];
        }
        __syncthreads();
    }

#pragma unroll
    for (int p = 0; p < 2; ++p) {
#pragma unroll
        for (int ii = 0; ii < 4; ++ii) {
            int row = bm + p * 64 + ty * 4 + ii;
#pragma unroll
            for (int q = 0; q < 2; ++q) {
                int col = bn + q * 64 + tx * 4;
                if (NGUARD && col >= N) continue;
                float4 v;
                float* vp = &v.x;
#pragma unroll
                for (int jj = 0; jj < 4; ++jj) {
                    float x = acc[p * 4 + ii][q * 4 + jj];
                    if (EPI == 1) {
                        x += bias[col + jj];
                        x = (x > 20.f) ? x : log1pf(__expf(x));
                    }
                    vp[jj] = x;
                }
                *(float4*)(C + (size_t)row * ldc + col) = v;
            }
        }
    }
}

// ---------------------------------------------------------------- split-K reduce
__global__ __launch_bounds__(256) void reduce8_kernel(
    const float* __restrict__ part, float* __restrict__ out, int n)
{
    int i = blockIdx.x * 256 + threadIdx.x;
    if (i < n) {
        float s = 0.f;
#pragma unroll
        for (int j = 0; j < 8; ++j) s += part[(size_t)j * n + i];
        out[i] = s;
    }
}

// ---------------------------------------------------------------- conv + SiLU
__global__ __launch_bounds__(256) void conv_silu_kernel(
    const float* __restrict__ XZu, const float* __restrict__ cw,
    const float* __restrict__ cb, float* __restrict__ U)
{
    int idx = blockIdx.x * 256 + threadIdx.x;
    int c4 = idx & 511;
    int row = idx >> 9;
    int t = row & (L_SEQ - 1);
    int c = c4 << 2;

    float4 acc;
    acc.x = cb[c]; acc.y = cb[c + 1]; acc.z = cb[c + 2]; acc.w = cb[c + 3];
    float4 w0 = *(const float4*)(cw + (size_t)(c + 0) * 4);
    float4 w1 = *(const float4*)(cw + (size_t)(c + 1) * 4);
    float4 w2 = *(const float4*)(cw + (size_t)(c + 2) * 4);
    float4 w3 = *(const float4*)(cw + (size_t)(c + 3) * 4);
#pragma unroll
    for (int k = 0; k < 4; ++k) {
        int tt = t - 3 + k;
        if (tt >= 0) {
            float4 xv = *(const float4*)(XZu + (size_t)(row - 3 + k) * DI + c);
            acc.x += xv.x * ((&w0.x)[k]);
            acc.y += xv.y * ((&w1.x)[k]);
            acc.z += xv.z * ((&w2.x)[k]);
            acc.w += xv.w * ((&w3.x)[k]);
        }
    }
    acc.x = acc.x / (1.f + __expf(-acc.x));
    acc.y = acc.y / (1.f + __expf(-acc.y));
    acc.z = acc.z / (1.f + __expf(-acc.z));
    acc.w = acc.w / (1.f + __expf(-acc.w));
    *(float4*)(U + (size_t)row * DI + c) = acc;
}

// ---------------------------------------------------------------- fused chunked scan
__global__ __launch_bounds__(256) void scan_fused(
    const float* __restrict__ U, const float* __restrict__ DELTA,
    const float* __restrict__ DBL, const float* __restrict__ ZF,
    const float* __restrict__ A_log, const float* __restrict__ Dskip,
    u16* __restrict__ Yb)
{
    __shared__ float ps[EL][NCH][DS][2];   // 32 KB (P,S)
    __shared__ float hs[EL][NCH][DS];      // 16 KB (h_start)

    const int tid   = threadIdx.x;
    const int el    = tid & (EL - 1);
    const int chunk = tid >> 3;            // 0..31
    const int bid   = blockIdx.x;
    const int b     = bid >> 8;            // DI/EL = 256 e-groups
    const int e     = (bid & 255) * EL + el;
    const int t0    = chunk * CHL;

    float Ae[DS];
#pragma unroll
    for (int s = 0; s < DS; ++s)
        Ae[s] = -__expf(A_log[(size_t)e * DS + s]);

    const float* up = U     + (size_t)b * L_SEQ * DI + e;
    const float* dp = DELTA + (size_t)b * L_SEQ * DI + e;
    const float* zp = ZF    + (size_t)b * L_SEQ * DI + e;
    const float* bp = DBL   + ((size_t)b * L_SEQ + t0) * DBLC + DTR;
    const float* cp = bp + DS;
    u16* yp = Yb + (size_t)b * L_SEQ * DI + e;

    // ---- phase A: per-chunk transfer function (P, S) per state
    float P[DS], S[DS];
#pragma unroll
    for (int s = 0; s < DS; ++s) { P[s] = 1.f; S[s] = 0.f; }

    {
        float u0 = up[(size_t)t0 * DI];
        float d0 = dp[(size_t)t0 * DI];
        float4 B0[4];
#pragma unroll
        for (int q = 0; q < 4; ++q) B0[q] = *(const float4*)(bp + q * 4);

        for (int i = 0; i < CHL; ++i) {
            float u1 = 0.f, d1 = 0.f;
            float4 B1[4] = {};
            if (i + 1 < CHL) {
                u1 = up[(size_t)(t0 + i + 1) * DI];
                d1 = dp[(size_t)(t0 + i + 1) * DI];
#pragma unroll
                for (int q = 0; q < 4; ++q)
                    B1[q] = *(const float4*)(bp + (i + 1) * DBLC + q * 4);
            }
            float du = d0 * u0;
            const float* Bf = (const float*)&B0[0];
#pragma unroll
            for (int s = 0; s < DS; ++s) {
                float a = __expf(d0 * Ae[s]);
                P[s] *= a;
                S[s] = S[s] * a + du * Bf[s];
            }
            u0 = u1; d0 = d1;
#pragma unroll
            for (int q = 0; q < 4; ++q) B0[q] = B1[q];
        }
    }
#pragma unroll
    for (int s = 0; s < DS; ++s) {
        ps[el][chunk][s][0] = P[s];
        ps[el][chunk][s][1] = S[s];
    }
    __syncthreads();

    // ---- phase B: in-LDS chunk prefix (same order as serial combine)
    if (tid < EL * DS) {
        int pel = tid >> 4;
        int s   = tid & 15;
        float h = 0.f;
#pragma unroll
        for (int c = 0; c < NCH; ++c) {
            hs[pel][c][s] = h;
            h = ps[pel][c][s][0] * h + ps[pel][c][s][1];
        }
    }
    __syncthreads();

    // ---- phase C: rescan from h_start, emit gated bf16 y
    float Dk = Dskip[e];
    float h[DS];
#pragma unroll
    for (int s = 0; s < DS; ++s) h[s] = hs[el][chunk][s];

    {
        float u0 = up[(size_t)t0 * DI];
        float d0 = dp[(size_t)t0 * DI];
        float z0 = zp[(size_t)t0 * DI];
        float4 B0[4], C0[4];
#pragma unroll
        for (int q = 0; q < 4; ++q) {
            B0[q] = *(const float4*)(bp + q * 4);
            C0[q] = *(const float4*)(cp + q * 4);
        }

        for (int i = 0; i < CHL; ++i) {
            float u1 = 0.f, d1 = 0.f, z1 = 0.f;
            float4 B1[4] = {}, C1[4] = {};
            if (i + 1 < CHL) {
                u1 = up[(size_t)(t0 + i + 1) * DI];
                d1 = dp[(size_t)(t0 + i + 1) * DI];
                z1 = zp[(size_t)(t0 + i + 1) * DI];
#pragma unroll
                for (int q = 0; q < 4; ++q) {
                    B1[q] = *(const float4*)(bp + (i + 1) * DBLC + q * 4);
                    C1[q] = *(const float4*)(cp + (i + 1) * DBLC + q * 4);
                }
            }
            float du = d0 * u0;
            const float* Bf = (const float*)&B0[0];
            const float* Cf = (const float*)&C0[0];
            float y0 = 0.f, y1 = 0.f, y2 = 0.f, y3 = 0.f;
#pragma unroll
            for (int s = 0; s < DS; ++s) {
                float a = __expf(d0 * Ae[s]);
                h[s] = h[s] * a + du * Bf[s];
                float hc = h[s] * Cf[s];
                if ((s & 3) == 0) y0 += hc;
                else if ((s & 3) == 1) y1 += hc;
                else if ((s & 3) == 2) y2 += hc;
                else y3 += hc;
            }
            float p = (y0 + y1) + (y2 + y3);
            float g = z0 / (1.f + __expf(-z0));
            yp[(size_t)(t0 + i) * DI] = f2bf((p + u0 * Dk) * g);
            u0 = u1; d0 = d1; z0 = z1;
#pragma unroll
            for (int q = 0; q < 4; ++q) { B0[q] = B1[q]; C0[q] = C1[q]; }
        }
    }
}

// ---------------------------------------------------------------- layernorm (bf16 out)
__global__ __launch_bounds__(256) void layernorm_kernel(
    const float* __restrict__ X, const float* __restrict__ g,
    const float* __restrict__ be, u16* __restrict__ XNb)
{
    __shared__ float red[4];
    int row = blockIdx.x;
    int tid = threadIdx.x;
    float4 v = ((const float4*)(X + (size_t)row * DM))[tid];

    float ssum = v.x + v.y + v.z + v.w;
#pragma unroll
    for (int o = 32; o >= 1; o >>= 1) ssum += __shfl_xor(ssum, o);
    if ((tid & 63) == 0) red[tid >> 6] = ssum;
    __syncthreads();
    float mean = (red[0] + red[1] + red[2] + red[3]) * (1.f / DM);
    __syncthreads();

    float dx = v.x - mean, dy = v.y - mean, dz = v.z - mean, dw = v.w - mean;
    float sq = dx * dx + dy * dy + dz * dz + dw * dw;
#pragma unroll
    for (int o = 32; o >= 1; o >>= 1) sq += __shfl_xor(sq, o);
    if ((tid & 63) == 0) red[tid >> 6] = sq;
    __syncthreads();
    float var = (red[0] + red[1] + red[2] + red[3]) * (1.f / DM);
    float rs = rsqrtf(var + 1e-5f);

    float4 gv = ((const float4*)g)[tid];
    float4 bv = ((const float4*)be)[tid];
    ushort4 o;
    o.x = f2bf(dx * rs * gv.x + bv.x);
    o.y = f2bf(dy * rs * gv.y + bv.y);
    o.z = f2bf(dz * rs * gv.z + bv.z);
    o.w = f2bf(dw * rs * gv.w + bv.w);
    ((ushort4*)(XNb + (size_t)row * DM))[tid] = o;
}

// ---------------------------------------------------------------- launch
extern "C" void kernel_launch(void* const* d_in, const int* in_sizes, int n_in,
                              void* d_out, int out_size, void* d_ws, size_t ws_size,
                              hipStream_t stream)
{
    const int*   tokens = (const int*)d_in[0];
    const float* emb    = (const float*)d_in[1];
    const float* in_w   = (const float*)d_in[2];
    const float* conv_w = (const float*)d_in[3];
    const float* conv_b = (const float*)d_in[4];
    const float* xp_w   = (const float*)d_in[5];
    const float* dt_w   = (const float*)d_in[6];
    const float* dt_b   = (const float*)d_in[7];
    const float* A_log  = (const float*)d_in[8];
    const float* Dskip  = (const float*)d_in[9];
    const float* out_w  = (const float*)d_in[10];
    const float* gamma  = (const float*)d_in[11];
    const float* beta   = (const float*)d_in[12];
    const float* lm_w   = (const float*)d_in[13];
    float* out = (float*)d_out;

    // ---- workspace: 43.39M floats = 173.6 MB (round-4..14-proven size).
    float* ws = (float*)d_ws;
    size_t off = 0;
    float* X     = ws + off; off += (size_t)BL * DM;        //  4.19M  fp32 LN input
    float* XZu   = ws + off; off += (size_t)BL * DI;        //  8.39M
    float* U     = ws + off; off += (size_t)BL * DI;        //  8.39M
    float* ZF    = ws + off; off += (size_t)BL * DI;        //  8.39M
    float* DELTA = ws + off; off += (size_t)BL * DI;        //  8.39M
    float* DBL   = ws + off; off += (size_t)BL * DBLC;      //  0.39M
    u16* Xb     = (u16*)(ws + off); off += (size_t)BL * DM / 2;      // 2.10M
    u16* wb_in  = (u16*)(ws + off); off += (size_t)2 * DI * DM / 2;  // 2.10M
    u16* wb_out = (u16*)(ws + off); off += (size_t)DM * DI / 2;      // 1.05M
    // aliases (lifetime-checked):
    u16* Yb    = (u16*)XZu;   // scan out; XZu dead after conv_silu
    u16* wb_lm = (u16*)XZu;   // over [XZu|U]; dead after layer-2 out_proj
    float* PART = DELTA;      // split-K partials; consumed before dt_proj
    u16* XNb   = Xb;          // LN out; Xb dead after layer-2 in_proj

    embed_kernel<<<BL, 256, 0, stream>>>(tokens, emb, Xb);

    const int SCAN_GRID = BATCH * (DI / EL);  // 512 blocks

    for (int l = 0; l < 2; ++l) {
        const float* cwp = conv_w + (size_t)l * DI * 4;
        const float* cbp = conv_b + (size_t)l * DI;
        const float* xw  = xp_w   + (size_t)l * DBLC * DI;
        const float* dw  = dt_w   + (size_t)l * DI * DTR;
        const float* dbp = dt_b   + (size_t)l * DI;
        const float* alp = A_log  + (size_t)l * DI * DS;
        const float* dkp = Dskip  + (size_t)l * DI;

        // both weight converts in one dispatch
        const int n8i = 2 * DI * DM / 8, n8o = DM * DI / 8;
        cvt2_bf16_kernel<<<(n8i + n8o + 255) / 256, 256, 0, stream>>>(
            in_w + (size_t)l * 2 * DI * DM, wb_in, n8i,
            out_w + (size_t)l * DM * DI, wb_out, n8o);

        // xz = x @ in_w^T : [4096,4096] K=1024; u-half -> XZu, z-half -> ZF
        gemm_8p<1><<<dim3(16, 16), 512, 0, stream>>>(
            Xb, DM, wb_in, DM, XZu, ZF, 0, DM);
        // u = silu(conv(XZu))
        conv_silu_kernel<<<(BL * DI / 4) / 256, 256, 0, stream>>>(XZu, cwp, cbp, U);
        // x_dbl = u @ xp_w^T : [4096,96] fp32 split-K
        sgemm_bt<0, true, true><<<dim3(1, 32, 8), 256, 0, stream>>>(
            U, DI, xw, DI, PART, DBLC, nullptr, BL, DBLC, DI, DI / 8);
        reduce8_kernel<<<(BL * DBLC + 255) / 256, 256, 0, stream>>>(
            PART, DBL, BL * DBLC);
        // delta = softplus(dt @ dt_w^T + dt_b) fp32 (K=64)
        sgemm_bt<1, false, false><<<dim3(16, 32), 256, 0, stream>>>(
            DBL, DBLC, dw, DTR, DELTA, DI, dbp, BL, DI, DTR, 0);
        // fused chunked scan -> bf16 Yb (aliases XZu)
        scan_fused<<<SCAN_GRID, 256, 0, stream>>>(
            U, DELTA, DBL, ZF, alp, dkp, Yb);
        // x = y @ out_w^T : [4096,1024] K=2048 (proven 128^2 2-phase)
        gemm_bb2<<<dim3(32, 8), 256, 0, stream>>>(
            Yb, DI, wb_out, DI, X, Xb, DM, DI);
    }

    cvt_bf16_kernel<<<((size_t)VOCAB * DM / 8 + 255) / 256, 256, 0, stream>>>(
        lm_w, wb_lm, VOCAB * DM / 8);

    layernorm_kernel<<<BL, 256, 0, stream>>>(X, gamma, beta, XNb);

    // logits = xn @ lm_head^T : [4096,32000] K=1024 (8-phase, NT stores)
    gemm_8p<0><<<dim3(16, 125), 512, 0, stream>>>(
        XNb, DM, wb_lm, DM, out, nullptr, VOCAB, DM);
}